// Round 1
// baseline (1945.697 us; speedup 1.0000x reference)
//
#include <hip/hip_runtime.h>

constexpr float BN_EPS = 1e-5f;

// ---------------- CSR build ----------------

__global__ __launch_bounds__(256) void k_hist(const int* __restrict__ dst, int E, int* __restrict__ cnt) {
  int i = blockIdx.x * blockDim.x + threadIdx.x;
  int stride = gridDim.x * blockDim.x;
  for (; i < E; i += stride) atomicAdd(&cnt[dst[i]], 1);
}

__global__ __launch_bounds__(1024) void k_scan1(const int* __restrict__ cnt, int N, int* __restrict__ rp, int* __restrict__ bsum) {
  __shared__ int sh[1024];
  int g = blockIdx.x * 1024 + threadIdx.x;
  int v = (g < N) ? cnt[g] : 0;
  sh[threadIdx.x] = v;
  __syncthreads();
  for (int off = 1; off < 1024; off <<= 1) {
    int t = (threadIdx.x >= off) ? sh[threadIdx.x - off] : 0;
    __syncthreads();
    sh[threadIdx.x] += t;
    __syncthreads();
  }
  if (g < N) rp[g] = sh[threadIdx.x] - v;            // exclusive within block
  if (threadIdx.x == 1023) bsum[blockIdx.x] = sh[1023];
}

__global__ __launch_bounds__(128) void k_scan2(int* __restrict__ bsum, int nb) {
  __shared__ int sh[128];
  int v = (threadIdx.x < nb) ? bsum[threadIdx.x] : 0;
  sh[threadIdx.x] = v;
  __syncthreads();
  for (int off = 1; off < 128; off <<= 1) {
    int t = (threadIdx.x >= off) ? sh[threadIdx.x - off] : 0;
    __syncthreads();
    sh[threadIdx.x] += t;
    __syncthreads();
  }
  if (threadIdx.x < nb) bsum[threadIdx.x] = sh[threadIdx.x] - v;  // exclusive block offsets
}

__global__ __launch_bounds__(256) void k_scan3(const int* __restrict__ cnt, int N, int* __restrict__ rp,
                                               const int* __restrict__ bsum, int* __restrict__ cursor,
                                               float* __restrict__ deg_inv) {
  int i = blockIdx.x * blockDim.x + threadIdx.x;
  if (i >= N) return;
  int r = rp[i] + bsum[i >> 10];
  rp[i] = r;
  cursor[i] = r;
  int c = cnt[i];
  deg_inv[i] = 1.0f / (float)max(c, 1);
}

__global__ __launch_bounds__(256) void k_scatter(const int* __restrict__ dst, const int* __restrict__ src, int E,
                                                 int* __restrict__ cursor, int* __restrict__ csr) {
  int i = blockIdx.x * blockDim.x + threadIdx.x;
  int stride = gridDim.x * blockDim.x;
  for (; i < E; i += stride) {
    int p = atomicAdd(&cursor[dst[i]], 1);
    csr[p] = src[i];
  }
}

// ---------------- aggregation (CSR gather, width 128) ----------------

__global__ __launch_bounds__(256) void k_agg128(const float* __restrict__ X, const int* __restrict__ rp,
                                                const int* __restrict__ cnt, const int* __restrict__ csr,
                                                const float* __restrict__ deg_inv, float* __restrict__ out, int N) {
  int node = blockIdx.x * 4 + (threadIdx.x >> 6);
  if (node >= N) return;
  int lane = threadIdx.x & 63;
  int start = rp[node];
  int c = cnt[node];
  const float2* X2 = reinterpret_cast<const float2*>(X);
  float ax = 0.f, ay = 0.f;
  int p = 0;
  for (; p + 1 < c; p += 2) {
    int s0 = csr[start + p];
    int s1 = csr[start + p + 1];
    float2 v0 = X2[(size_t)s0 * 64 + lane];
    float2 v1 = X2[(size_t)s1 * 64 + lane];
    ax += v0.x + v1.x;
    ay += v0.y + v1.y;
  }
  if (p < c) {
    int s0 = csr[start + p];
    float2 v0 = X2[(size_t)s0 * 64 + lane];
    ax += v0.x;
    ay += v0.y;
  }
  float di = deg_inv[node];
  reinterpret_cast<float2*>(out)[(size_t)node * 64 + lane] = make_float2(ax * di, ay * di);
}

// ---------------- dual GEMM: Z = A@WA^T + B@WB^T + bias  (K=128, F=128) ----------------

__global__ __launch_bounds__(256) void k_gemm_dual(const float* __restrict__ A, const float* B,
                                                   const float* __restrict__ WA, const float* __restrict__ WB,
                                                   const float* __restrict__ bias, float* Z, int M) {
  constexpr int TM = 32, KT = 16;
  __shared__ float sA[KT][TM + 1];
  __shared__ float sB[KT][TM + 1];
  __shared__ float sWA[KT][128];
  __shared__ float sWB[KT][128];
  const int tid = threadIdx.x;
  const int row0 = blockIdx.x * TM;
  const int tx = tid & 31;   // col group: cols tx*4 .. tx*4+3
  const int ty = tid >> 5;   // row group: rows ty*4 .. ty*4+3 (ty in 0..7)
  float acc[4][4] = {};
  for (int k0 = 0; k0 < 128; k0 += KT) {
    __syncthreads();
    for (int e = tid; e < TM * KT; e += 256) {
      int r = e >> 4, k = e & 15;
      int gr = row0 + r;
      if (gr >= M) gr = M - 1;
      size_t gi = (size_t)gr * 128 + k0 + k;
      sA[k][r] = A[gi];
      sB[k][r] = B[gi];
    }
    for (int e = tid; e < 128 * KT; e += 256) {
      int f = e >> 4, k = e & 15;
      int gi = f * 128 + k0 + k;
      sWA[k][f] = WA[gi];
      sWB[k][f] = WB[gi];
    }
    __syncthreads();
#pragma unroll
    for (int k = 0; k < KT; ++k) {
      float4 wa = *reinterpret_cast<const float4*>(&sWA[k][tx * 4]);
      float4 wb = *reinterpret_cast<const float4*>(&sWB[k][tx * 4]);
#pragma unroll
      for (int r = 0; r < 4; ++r) {
        float a = sA[k][ty * 4 + r];
        float b = sB[k][ty * 4 + r];
        acc[r][0] = fmaf(a, wa.x, fmaf(b, wb.x, acc[r][0]));
        acc[r][1] = fmaf(a, wa.y, fmaf(b, wb.y, acc[r][1]));
        acc[r][2] = fmaf(a, wa.z, fmaf(b, wb.z, acc[r][2]));
        acc[r][3] = fmaf(a, wa.w, fmaf(b, wb.w, acc[r][3]));
      }
    }
  }
  float4 bv = *reinterpret_cast<const float4*>(&bias[tx * 4]);
#pragma unroll
  for (int r = 0; r < 4; ++r) {
    int row = row0 + ty * 4 + r;
    if (row < M) {
      float4 o = make_float4(acc[r][0] + bv.x, acc[r][1] + bv.y, acc[r][2] + bv.z, acc[r][3] + bv.w);
      *reinterpret_cast<float4*>(&Z[(size_t)row * 128 + tx * 4]) = o;
    }
  }
}

// ---------------- BatchNorm (training stats) + ReLU ----------------

__global__ __launch_bounds__(256) void k_bn_stats(const float* __restrict__ Z, int M, float* __restrict__ sums) {
  const int f = threadIdx.x & 127;
  const int half = threadIdx.x >> 7;
  const int r0 = blockIdx.x * 1024;
  const int r1 = min(r0 + 1024, M);
  float s = 0.f, s2 = 0.f;
  for (int r = r0 + half; r < r1; r += 2) {
    float v = Z[(size_t)r * 128 + f];
    s += v;
    s2 = fmaf(v, v, s2);
  }
  __shared__ float ls[256];
  ls[threadIdx.x] = s;
  __syncthreads();
  if (half == 0) atomicAdd(&sums[f], ls[f] + ls[f + 128]);
  __syncthreads();
  ls[threadIdx.x] = s2;
  __syncthreads();
  if (half == 0) atomicAdd(&sums[128 + f], ls[f] + ls[f + 128]);
}

__global__ __launch_bounds__(128) void k_bn_finalize(const float* __restrict__ sums, const float* __restrict__ g,
                                                     const float* __restrict__ b, int M, float* __restrict__ ss) {
  int f = threadIdx.x;
  float inv = 1.0f / (float)M;
  float mean = sums[f] * inv;
  float var = sums[128 + f] * inv - mean * mean;
  var = fmaxf(var, 0.f);
  float sc = g[f] * rsqrtf(var + BN_EPS);
  ss[f] = sc;
  ss[128 + f] = fmaf(-mean, sc, b[f]);
}

__global__ __launch_bounds__(256) void k_bn_relu(float* Z, int M, const float* __restrict__ ss) {
  int n4 = M * 32;
  for (int i = blockIdx.x * blockDim.x + threadIdx.x; i < n4; i += gridDim.x * blockDim.x) {
    float4 v = reinterpret_cast<float4*>(Z)[i];
    int f0 = (i & 31) * 4;
    float4 sc = *reinterpret_cast<const float4*>(&ss[f0]);
    float4 sh = *reinterpret_cast<const float4*>(&ss[128 + f0]);
    v.x = fmaxf(fmaf(v.x, sc.x, sh.x), 0.f);
    v.y = fmaxf(fmaf(v.y, sc.y, sh.y), 0.f);
    v.z = fmaxf(fmaf(v.z, sc.z, sh.z), 0.f);
    v.w = fmaxf(fmaf(v.w, sc.w, sh.w), 0.f);
    reinterpret_cast<float4*>(Z)[i] = v;
  }
}

// ---------------- layer 2: Y = H@Wl2^T, R = H@Wr2^T (C outputs, one wave per row) ----------------

__global__ __launch_bounds__(256) void k_gemm2_47(const float* __restrict__ H, const float* __restrict__ WA,
                                                  const float* __restrict__ WB, float* __restrict__ Y,
                                                  float* __restrict__ R, int M, int C) {
  int row = blockIdx.x * 4 + (threadIdx.x >> 6);
  int lane = threadIdx.x & 63;
  if (row >= M) return;
  if (lane < C) {
    const float4* h4 = reinterpret_cast<const float4*>(H + (size_t)row * 128);
    const float4* wa4 = reinterpret_cast<const float4*>(WA + (size_t)lane * 128);
    const float4* wb4 = reinterpret_cast<const float4*>(WB + (size_t)lane * 128);
    float accY = 0.f, accR = 0.f;
#pragma unroll 8
    for (int k = 0; k < 32; ++k) {
      float4 h = h4[k];
      float4 a = wa4[k];
      float4 b = wb4[k];
      accY += h.x * a.x + h.y * a.y + h.z * a.z + h.w * a.w;
      accR += h.x * b.x + h.y * b.y + h.z * b.z + h.w * b.w;
    }
    Y[(size_t)row * C + lane] = accY;
    R[(size_t)row * C + lane] = accR;
  }
}

__global__ __launch_bounds__(256) void k_agg47(const float* __restrict__ Y, const float* __restrict__ R,
                                               const float* __restrict__ bias, const int* __restrict__ rp,
                                               const int* __restrict__ cnt, const int* __restrict__ csr,
                                               const float* __restrict__ deg_inv, float* __restrict__ out,
                                               int N, int C) {
  int node = blockIdx.x * 4 + (threadIdx.x >> 6);
  int lane = threadIdx.x & 63;
  if (node >= N) return;
  int start = rp[node];
  int c = cnt[node];
  if (lane < C) {
    float acc = 0.f;
    for (int p = 0; p < c; ++p) {
      int s = csr[start + p];
      acc += Y[(size_t)s * C + lane];
    }
    out[(size_t)node * C + lane] = fmaf(acc, deg_inv[node], R[(size_t)node * C + lane] + bias[lane]);
  }
}

// ---------------- host launch ----------------

extern "C" void kernel_launch(void* const* d_in, const int* in_sizes, int n_in,
                              void* d_out, int out_size, void* d_ws, size_t ws_size,
                              hipStream_t stream) {
  const float* x   = (const float*)d_in[0];
  const int*   ei  = (const int*)d_in[1];
  const float* Wl0 = (const float*)d_in[2];
  const float* bl0 = (const float*)d_in[3];
  const float* Wr0 = (const float*)d_in[4];
  const float* g0  = (const float*)d_in[5];
  const float* b0  = (const float*)d_in[6];
  const float* Wl1 = (const float*)d_in[7];
  const float* bl1 = (const float*)d_in[8];
  const float* Wr1 = (const float*)d_in[9];
  const float* g1  = (const float*)d_in[10];
  const float* b1  = (const float*)d_in[11];
  const float* Wl2 = (const float*)d_in[12];
  const float* bl2 = (const float*)d_in[13];
  const float* Wr2 = (const float*)d_in[14];

  const int N = in_sizes[0] / 128;
  const int E = in_sizes[1] / 2;
  const int C = in_sizes[13];  // 47

  const int* edst = ei;
  const int* esrc = ei + E;

  char* w = (char*)d_ws;
  auto al = [](size_t v) { return (v + 255) & ~(size_t)255; };
  size_t off = 0;
  int*   cnt     = (int*)(w + off);   off = al(off + (size_t)N * 4);
  int*   rp      = (int*)(w + off);   off = al(off + (size_t)N * 4);
  int*   cursor  = (int*)(w + off);   off = al(off + (size_t)N * 4);
  float* deg_inv = (float*)(w + off); off = al(off + (size_t)N * 4);
  int*   bsum    = (int*)(w + off);   off = al(off + 1024);
  float* stats   = (float*)(w + off); off = al(off + 512 * 4);
  int*   csr     = (int*)(w + off);   off = al(off + (size_t)E * 4);
  float* bufA    = (float*)(w + off); off = al(off + (size_t)N * 128 * 4);
  float* bufB    = (float*)(w + off); off = al(off + (size_t)N * 128 * 4);
  float* Yb = bufA;
  float* Rb = bufA + (size_t)N * C;

  const int nb = (N + 1023) / 1024;
  const int aggGrid = (N + 3) / 4;
  const int gemmGrid = (N + 31) / 32;

  // CSR build (once per call; reused by all 3 layers)
  hipMemsetAsync(cnt, 0, (size_t)N * 4, stream);
  k_hist<<<1024, 256, 0, stream>>>(edst, E, cnt);
  k_scan1<<<nb, 1024, 0, stream>>>(cnt, N, rp, bsum);
  k_scan2<<<1, 128, 0, stream>>>(bsum, nb);
  k_scan3<<<(N + 255) / 256, 256, 0, stream>>>(cnt, N, rp, bsum, cursor, deg_inv);
  k_scatter<<<1024, 256, 0, stream>>>(edst, esrc, E, cursor, csr);

  // Layer 0
  k_agg128<<<aggGrid, 256, 0, stream>>>(x, rp, cnt, csr, deg_inv, bufA, N);
  k_gemm_dual<<<gemmGrid, 256, 0, stream>>>(bufA, x, Wl0, Wr0, bl0, bufB, N);
  hipMemsetAsync(stats, 0, 256 * 4, stream);
  k_bn_stats<<<nb, 256, 0, stream>>>(bufB, N, stats);
  k_bn_finalize<<<1, 128, 0, stream>>>(stats, g0, b0, N, stats + 256);
  k_bn_relu<<<2048, 256, 0, stream>>>(bufB, N, stats + 256);

  // Layer 1 (GEMM in place into bufB: each block reads its rows fully before writing)
  k_agg128<<<aggGrid, 256, 0, stream>>>(bufB, rp, cnt, csr, deg_inv, bufA, N);
  k_gemm_dual<<<gemmGrid, 256, 0, stream>>>(bufA, bufB, Wl1, Wr1, bl1, bufB, N);
  hipMemsetAsync(stats, 0, 256 * 4, stream);
  k_bn_stats<<<nb, 256, 0, stream>>>(bufB, N, stats);
  k_bn_finalize<<<1, 128, 0, stream>>>(stats, g1, b1, N, stats + 256);
  k_bn_relu<<<2048, 256, 0, stream>>>(bufB, N, stats + 256);

  // Layer 2: transform first (mean is linear), aggregate in C=47-dim space
  k_gemm2_47<<<aggGrid, 256, 0, stream>>>(bufB, Wl2, Wr2, Yb, Rb, N, C);
  k_agg47<<<aggGrid, 256, 0, stream>>>(Yb, Rb, bl2, rp, cnt, csr, deg_inv, (float*)d_out, N, C);
}

// Round 2
// 911.845 us; speedup vs baseline: 2.1338x; 2.1338x over previous
//
#include <hip/hip_runtime.h>

constexpr float BN_EPS = 1e-5f;

// ---------------- CSR build ----------------

__global__ __launch_bounds__(256) void k_hist(const int* __restrict__ dst, int E, int* __restrict__ cnt) {
  int i = blockIdx.x * blockDim.x + threadIdx.x;
  int stride = gridDim.x * blockDim.x;
  for (; i < E; i += stride) atomicAdd(&cnt[dst[i]], 1);
}

__global__ __launch_bounds__(1024) void k_scan1(const int* __restrict__ cnt, int N, int* __restrict__ rp, int* __restrict__ bsum) {
  __shared__ int sh[1024];
  int g = blockIdx.x * 1024 + threadIdx.x;
  int v = (g < N) ? cnt[g] : 0;
  sh[threadIdx.x] = v;
  __syncthreads();
  for (int off = 1; off < 1024; off <<= 1) {
    int t = (threadIdx.x >= off) ? sh[threadIdx.x - off] : 0;
    __syncthreads();
    sh[threadIdx.x] += t;
    __syncthreads();
  }
  if (g < N) rp[g] = sh[threadIdx.x] - v;            // exclusive within block
  if (threadIdx.x == 1023) bsum[blockIdx.x] = sh[1023];
}

__global__ __launch_bounds__(128) void k_scan2(int* __restrict__ bsum, int nb) {
  __shared__ int sh[128];
  int v = (threadIdx.x < nb) ? bsum[threadIdx.x] : 0;
  sh[threadIdx.x] = v;
  __syncthreads();
  for (int off = 1; off < 128; off <<= 1) {
    int t = (threadIdx.x >= off) ? sh[threadIdx.x - off] : 0;
    __syncthreads();
    sh[threadIdx.x] += t;
    __syncthreads();
  }
  if (threadIdx.x < nb) bsum[threadIdx.x] = sh[threadIdx.x] - v;  // exclusive block offsets
}

__global__ __launch_bounds__(256) void k_scan3(const int* __restrict__ cnt, int N, int* __restrict__ rp,
                                               const int* __restrict__ bsum, int* __restrict__ cursor,
                                               float* __restrict__ deg_inv) {
  int i = blockIdx.x * blockDim.x + threadIdx.x;
  if (i >= N) return;
  int r = rp[i] + bsum[i >> 10];
  rp[i] = r;
  cursor[i] = r;
  int c = cnt[i];
  deg_inv[i] = 1.0f / (float)max(c, 1);
}

__global__ __launch_bounds__(256) void k_scatter(const int* __restrict__ dst, const int* __restrict__ src, int E,
                                                 int* __restrict__ cursor, int* __restrict__ csr) {
  int i = blockIdx.x * blockDim.x + threadIdx.x;
  int stride = gridDim.x * blockDim.x;
  for (; i < E; i += stride) {
    int p = atomicAdd(&cursor[dst[i]], 1);
    csr[p] = src[i];
  }
}

// ---------------- aggregation (CSR gather, width 128) ----------------

__global__ __launch_bounds__(256) void k_agg128(const float* __restrict__ X, const int* __restrict__ rp,
                                                const int* __restrict__ cnt, const int* __restrict__ csr,
                                                const float* __restrict__ deg_inv, float* __restrict__ out, int N) {
  int node = blockIdx.x * 4 + (threadIdx.x >> 6);
  if (node >= N) return;
  int lane = threadIdx.x & 63;
  int start = rp[node];
  int c = cnt[node];
  const float2* X2 = reinterpret_cast<const float2*>(X);
  float ax = 0.f, ay = 0.f;
  int p = 0;
  for (; p + 3 < c; p += 4) {
    int s0 = csr[start + p];
    int s1 = csr[start + p + 1];
    int s2 = csr[start + p + 2];
    int s3 = csr[start + p + 3];
    float2 v0 = X2[(size_t)s0 * 64 + lane];
    float2 v1 = X2[(size_t)s1 * 64 + lane];
    float2 v2 = X2[(size_t)s2 * 64 + lane];
    float2 v3 = X2[(size_t)s3 * 64 + lane];
    ax += (v0.x + v1.x) + (v2.x + v3.x);
    ay += (v0.y + v1.y) + (v2.y + v3.y);
  }
  for (; p < c; ++p) {
    int s0 = csr[start + p];
    float2 v0 = X2[(size_t)s0 * 64 + lane];
    ax += v0.x;
    ay += v0.y;
  }
  float di = deg_inv[node];
  reinterpret_cast<float2*>(out)[(size_t)node * 64 + lane] = make_float2(ax * di, ay * di);
}

// ---------------- dual GEMM: Z = A@WA^T + B@WB^T + bias  (K=128, F=128) ----------------

__global__ __launch_bounds__(256) void k_gemm_dual(const float* __restrict__ A, const float* B,
                                                   const float* __restrict__ WA, const float* __restrict__ WB,
                                                   const float* __restrict__ bias, float* Z, int M) {
  constexpr int TM = 32, KT = 16;
  __shared__ float sA[KT][TM + 1];
  __shared__ float sB[KT][TM + 1];
  __shared__ float sWA[KT][128];
  __shared__ float sWB[KT][128];
  const int tid = threadIdx.x;
  const int row0 = blockIdx.x * TM;
  const int tx = tid & 31;   // col group: cols tx*4 .. tx*4+3
  const int ty = tid >> 5;   // row group: rows ty*4 .. ty*4+3 (ty in 0..7)
  float acc[4][4] = {};
  for (int k0 = 0; k0 < 128; k0 += KT) {
    __syncthreads();
    {
      // A,B tiles: 32 rows x 16 k = 128 float4 each; waves 0-1 -> A, waves 2-3 -> B
      int e = tid & 127;
      int r = e >> 2, kq = e & 3;
      int gr = row0 + r;
      if (gr >= M) gr = M - 1;
      size_t gi = (size_t)gr * 128 + k0 + kq * 4;
      if (tid < 128) {
        float4 v = *reinterpret_cast<const float4*>(&A[gi]);
        sA[kq * 4 + 0][r] = v.x; sA[kq * 4 + 1][r] = v.y;
        sA[kq * 4 + 2][r] = v.z; sA[kq * 4 + 3][r] = v.w;
      } else {
        float4 v = *reinterpret_cast<const float4*>(&B[gi]);
        sB[kq * 4 + 0][r] = v.x; sB[kq * 4 + 1][r] = v.y;
        sB[kq * 4 + 2][r] = v.z; sB[kq * 4 + 3][r] = v.w;
      }
    }
    for (int e = tid; e < 512; e += 256) {
      // weight tiles: 128 f x 16 k = 512 float4 each
      int f = e >> 2, kq = e & 3;
      size_t gi = (size_t)f * 128 + k0 + kq * 4;
      float4 va = *reinterpret_cast<const float4*>(&WA[gi]);
      sWA[kq * 4 + 0][f] = va.x; sWA[kq * 4 + 1][f] = va.y;
      sWA[kq * 4 + 2][f] = va.z; sWA[kq * 4 + 3][f] = va.w;
      float4 vb = *reinterpret_cast<const float4*>(&WB[gi]);
      sWB[kq * 4 + 0][f] = vb.x; sWB[kq * 4 + 1][f] = vb.y;
      sWB[kq * 4 + 2][f] = vb.z; sWB[kq * 4 + 3][f] = vb.w;
    }
    __syncthreads();
#pragma unroll
    for (int k = 0; k < KT; ++k) {
      float4 wa = *reinterpret_cast<const float4*>(&sWA[k][tx * 4]);
      float4 wb = *reinterpret_cast<const float4*>(&sWB[k][tx * 4]);
#pragma unroll
      for (int r = 0; r < 4; ++r) {
        float a = sA[k][ty * 4 + r];
        float b = sB[k][ty * 4 + r];
        acc[r][0] = fmaf(a, wa.x, fmaf(b, wb.x, acc[r][0]));
        acc[r][1] = fmaf(a, wa.y, fmaf(b, wb.y, acc[r][1]));
        acc[r][2] = fmaf(a, wa.z, fmaf(b, wb.z, acc[r][2]));
        acc[r][3] = fmaf(a, wa.w, fmaf(b, wb.w, acc[r][3]));
      }
    }
  }
  float4 bv = *reinterpret_cast<const float4*>(&bias[tx * 4]);
#pragma unroll
  for (int r = 0; r < 4; ++r) {
    int row = row0 + ty * 4 + r;
    if (row < M) {
      float4 o = make_float4(acc[r][0] + bv.x, acc[r][1] + bv.y, acc[r][2] + bv.z, acc[r][3] + bv.w);
      *reinterpret_cast<float4*>(&Z[(size_t)row * 128 + tx * 4]) = o;
    }
  }
}

// ---------------- BatchNorm (training stats) + ReLU ----------------

__global__ __launch_bounds__(256) void k_bn_stats(const float* __restrict__ Z, int M, float* __restrict__ sums) {
  const int f = threadIdx.x & 127;
  const int half = threadIdx.x >> 7;
  const int r0 = blockIdx.x * 256;
  const int r1 = min(r0 + 256, M);
  float s = 0.f, s2 = 0.f;
  for (int r = r0 + half; r < r1; r += 2) {
    float v = Z[(size_t)r * 128 + f];
    s += v;
    s2 = fmaf(v, v, s2);
  }
  __shared__ float ls[256];
  ls[threadIdx.x] = s;
  __syncthreads();
  if (half == 0) atomicAdd(&sums[f], ls[f] + ls[f + 128]);
  __syncthreads();
  ls[threadIdx.x] = s2;
  __syncthreads();
  if (half == 0) atomicAdd(&sums[128 + f], ls[f] + ls[f + 128]);
}

__global__ __launch_bounds__(128) void k_bn_finalize(const float* __restrict__ sums, const float* __restrict__ g,
                                                     const float* __restrict__ b, int M, float* __restrict__ ss) {
  int f = threadIdx.x;
  float inv = 1.0f / (float)M;
  float mean = sums[f] * inv;
  float var = sums[128 + f] * inv - mean * mean;
  var = fmaxf(var, 0.f);
  float sc = g[f] * rsqrtf(var + BN_EPS);
  ss[f] = sc;
  ss[128 + f] = fmaf(-mean, sc, b[f]);
}

__global__ __launch_bounds__(256) void k_bn_relu(float* Z, int M, const float* __restrict__ ss) {
  int n4 = M * 32;
  for (int i = blockIdx.x * blockDim.x + threadIdx.x; i < n4; i += gridDim.x * blockDim.x) {
    float4 v = reinterpret_cast<float4*>(Z)[i];
    int f0 = (i & 31) * 4;
    float4 sc = *reinterpret_cast<const float4*>(&ss[f0]);
    float4 sh = *reinterpret_cast<const float4*>(&ss[128 + f0]);
    v.x = fmaxf(fmaf(v.x, sc.x, sh.x), 0.f);
    v.y = fmaxf(fmaf(v.y, sc.y, sh.y), 0.f);
    v.z = fmaxf(fmaf(v.z, sc.z, sh.z), 0.f);
    v.w = fmaxf(fmaf(v.w, sc.w, sh.w), 0.f);
    reinterpret_cast<float4*>(Z)[i] = v;
  }
}

// ---------------- layer 2 transform: Z = H @ Wc^T, Wc[128][128] prepacked ----------------

__global__ __launch_bounds__(256) void k_prep_w2(const float* __restrict__ Wl2, const float* __restrict__ Wr2,
                                                 float* __restrict__ Wc, int C) {
  int i = blockIdx.x * 256 + threadIdx.x;  // 16384
  int r = i >> 7, k = i & 127;
  float v = 0.f;
  if (r < C) v = Wl2[r * 128 + k];
  else if (r >= 64 && r < 64 + C) v = Wr2[(r - 64) * 128 + k];
  Wc[i] = v;
}

__global__ __launch_bounds__(256) void k_gemm_single(const float* __restrict__ H, const float* __restrict__ Wc,
                                                     float* __restrict__ Z, int M) {
  constexpr int TM = 64, KT = 16;
  __shared__ float sA[KT][TM + 1];
  __shared__ float sW[KT][128];
  const int tid = threadIdx.x;
  const int row0 = blockIdx.x * TM;
  const int tx = tid & 31;   // col group: cols tx*4..+3
  const int ty = tid >> 5;   // row group: rows ty*8..+7
  float acc[8][4] = {};
  for (int k0 = 0; k0 < 128; k0 += KT) {
    __syncthreads();
    {
      // A tile: 64 rows x 16 k = 256 float4 -> 1 per thread
      int r = tid >> 2, kq = tid & 3;
      int gr = row0 + r;
      if (gr >= M) gr = M - 1;
      float4 v = *reinterpret_cast<const float4*>(&H[(size_t)gr * 128 + k0 + kq * 4]);
      sA[kq * 4 + 0][r] = v.x; sA[kq * 4 + 1][r] = v.y;
      sA[kq * 4 + 2][r] = v.z; sA[kq * 4 + 3][r] = v.w;
    }
    for (int e = tid; e < 512; e += 256) {
      int f = e >> 2, kq = e & 3;
      float4 v = *reinterpret_cast<const float4*>(&Wc[(size_t)f * 128 + k0 + kq * 4]);
      sW[kq * 4 + 0][f] = v.x; sW[kq * 4 + 1][f] = v.y;
      sW[kq * 4 + 2][f] = v.z; sW[kq * 4 + 3][f] = v.w;
    }
    __syncthreads();
#pragma unroll
    for (int k = 0; k < KT; ++k) {
      float4 w = *reinterpret_cast<const float4*>(&sW[k][tx * 4]);
#pragma unroll
      for (int r = 0; r < 8; ++r) {
        float a = sA[k][ty * 8 + r];
        acc[r][0] = fmaf(a, w.x, acc[r][0]);
        acc[r][1] = fmaf(a, w.y, acc[r][1]);
        acc[r][2] = fmaf(a, w.z, acc[r][2]);
        acc[r][3] = fmaf(a, w.w, acc[r][3]);
      }
    }
  }
#pragma unroll
  for (int r = 0; r < 8; ++r) {
    int row = row0 + ty * 8 + r;
    if (row < M) {
      float4 o = make_float4(acc[r][0], acc[r][1], acc[r][2], acc[r][3]);
      *reinterpret_cast<float4*>(&Z[(size_t)row * 128 + tx * 4]) = o;
    }
  }
}

// Z rows: cols 0..C-1 = Y (to aggregate), cols 64..64+C-1 = R (self term)
__global__ __launch_bounds__(256) void k_agg47(const float* __restrict__ Z, const float* __restrict__ bias,
                                               const int* __restrict__ rp, const int* __restrict__ cnt,
                                               const int* __restrict__ csr, const float* __restrict__ deg_inv,
                                               float* __restrict__ out, int N, int C) {
  int node = blockIdx.x * 4 + (threadIdx.x >> 6);
  int lane = threadIdx.x & 63;
  if (node >= N) return;
  int start = rp[node];
  int c = cnt[node];
  if (lane < C) {
    float acc = 0.f;
    int p = 0;
    for (; p + 1 < c; p += 2) {
      int s0 = csr[start + p];
      int s1 = csr[start + p + 1];
      acc += Z[(size_t)s0 * 128 + lane] + Z[(size_t)s1 * 128 + lane];
    }
    if (p < c) acc += Z[(size_t)csr[start + p] * 128 + lane];
    float self = Z[(size_t)node * 128 + 64 + lane];
    out[(size_t)node * C + lane] = fmaf(acc, deg_inv[node], self + bias[lane]);
  }
}

// ---------------- host launch ----------------

extern "C" void kernel_launch(void* const* d_in, const int* in_sizes, int n_in,
                              void* d_out, int out_size, void* d_ws, size_t ws_size,
                              hipStream_t stream) {
  const float* x   = (const float*)d_in[0];
  const int*   ei  = (const int*)d_in[1];
  const float* Wl0 = (const float*)d_in[2];
  const float* bl0 = (const float*)d_in[3];
  const float* Wr0 = (const float*)d_in[4];
  const float* g0  = (const float*)d_in[5];
  const float* b0  = (const float*)d_in[6];
  const float* Wl1 = (const float*)d_in[7];
  const float* bl1 = (const float*)d_in[8];
  const float* Wr1 = (const float*)d_in[9];
  const float* g1  = (const float*)d_in[10];
  const float* b1  = (const float*)d_in[11];
  const float* Wl2 = (const float*)d_in[12];
  const float* bl2 = (const float*)d_in[13];
  const float* Wr2 = (const float*)d_in[14];

  const int N = in_sizes[0] / 128;
  const int E = in_sizes[1] / 2;
  const int C = in_sizes[13];  // 47

  const int* edst = ei;
  const int* esrc = ei + E;

  char* w = (char*)d_ws;
  auto al = [](size_t v) { return (v + 255) & ~(size_t)255; };
  size_t off = 0;
  int*   cnt     = (int*)(w + off);   off = al(off + (size_t)N * 4);
  int*   rp      = (int*)(w + off);   off = al(off + (size_t)N * 4);
  int*   cursor  = (int*)(w + off);   off = al(off + (size_t)N * 4);
  float* deg_inv = (float*)(w + off); off = al(off + (size_t)N * 4);
  int*   bsum    = (int*)(w + off);   off = al(off + 1024);
  float* stats   = (float*)(w + off); off = al(off + 512 * 4);
  float* Wc      = (float*)(w + off); off = al(off + 128 * 128 * 4);
  int*   csr     = (int*)(w + off);   off = al(off + (size_t)E * 4);
  float* bufA    = (float*)(w + off); off = al(off + (size_t)N * 128 * 4);
  float* bufB    = (float*)(w + off); off = al(off + (size_t)N * 128 * 4);

  const int nb = (N + 1023) / 1024;
  const int aggGrid = (N + 3) / 4;
  const int gemmGrid = (N + 31) / 32;
  const int gemm1Grid = (N + 63) / 64;

  // CSR build (once per call; reused by all 3 layers)
  hipMemsetAsync(cnt, 0, (size_t)N * 4, stream);
  k_hist<<<1024, 256, 0, stream>>>(edst, E, cnt);
  k_scan1<<<nb, 1024, 0, stream>>>(cnt, N, rp, bsum);
  k_scan2<<<1, 128, 0, stream>>>(bsum, nb);
  k_scan3<<<(N + 255) / 256, 256, 0, stream>>>(cnt, N, rp, bsum, cursor, deg_inv);
  k_scatter<<<1024, 256, 0, stream>>>(edst, esrc, E, cursor, csr);
  k_prep_w2<<<64, 256, 0, stream>>>(Wl2, Wr2, Wc, C);

  // Layer 0
  k_agg128<<<aggGrid, 256, 0, stream>>>(x, rp, cnt, csr, deg_inv, bufA, N);
  k_gemm_dual<<<gemmGrid, 256, 0, stream>>>(bufA, x, Wl0, Wr0, bl0, bufB, N);
  hipMemsetAsync(stats, 0, 256 * 4, stream);
  k_bn_stats<<<(N + 255) / 256, 256, 0, stream>>>(bufB, N, stats);
  k_bn_finalize<<<1, 128, 0, stream>>>(stats, g0, b0, N, stats + 256);
  k_bn_relu<<<2048, 256, 0, stream>>>(bufB, N, stats + 256);

  // Layer 1 (GEMM in place into bufB: each block reads only its own rows before writing them)
  k_agg128<<<aggGrid, 256, 0, stream>>>(bufB, rp, cnt, csr, deg_inv, bufA, N);
  k_gemm_dual<<<gemmGrid, 256, 0, stream>>>(bufA, bufB, Wl1, Wr1, bl1, bufB, N);
  hipMemsetAsync(stats, 0, 256 * 4, stream);
  k_bn_stats<<<(N + 255) / 256, 256, 0, stream>>>(bufB, N, stats);
  k_bn_finalize<<<1, 128, 0, stream>>>(stats, g1, b1, N, stats + 256);
  k_bn_relu<<<2048, 256, 0, stream>>>(bufB, N, stats + 256);

  // Layer 2: transform first (mean is linear), aggregate in C-dim space
  k_gemm_single<<<gemm1Grid, 256, 0, stream>>>(bufB, Wc, bufA, N);
  k_agg47<<<aggGrid, 256, 0, stream>>>(bufA, bl2, rp, cnt, csr, deg_inv, (float*)d_out, N, C);
}

// Round 3
// 534.412 us; speedup vs baseline: 3.6408x; 1.7063x over previous
//
#include <hip/hip_runtime.h>

typedef __attribute__((ext_vector_type(8))) short short8;
typedef __attribute__((ext_vector_type(4))) float f32x4;

constexpr float BN_EPS = 1e-5f;
#define NBUCKETS 128  // buckets of 1024 nodes; N <= 131072

__device__ __forceinline__ ushort f2bf(float f) {
  uint u = __float_as_uint(f);
  u = (u + 0x7fffu + ((u >> 16) & 1u)) >> 16;
  return (ushort)u;
}
__device__ __forceinline__ float bf2f(ushort h) { return __uint_as_float((uint)h << 16); }
__device__ __forceinline__ float bf2f_lo(uint v) { return __uint_as_float(v << 16); }
__device__ __forceinline__ float bf2f_hi(uint v) { return __uint_as_float(v & 0xffff0000u); }

// ---------------- fp32 -> bf16 cast (x and weights) ----------------

__global__ __launch_bounds__(256) void k_cast(const float* __restrict__ in, ushort* __restrict__ out, int n4) {
  for (int i = blockIdx.x * 256 + threadIdx.x; i < n4; i += gridDim.x * 256) {
    float4 v = reinterpret_cast<const float4*>(in)[i];
    ushort4 o;
    o.x = f2bf(v.x); o.y = f2bf(v.y); o.z = f2bf(v.z); o.w = f2bf(v.w);
    reinterpret_cast<ushort4*>(out)[i] = o;
  }
}

// pack layer-2 weights: rows 0..C-1 = Wl2, rows 64..64+C-1 = Wr2, rest 0
__global__ __launch_bounds__(256) void k_prep_w2(const float* __restrict__ Wl2, const float* __restrict__ Wr2,
                                                 ushort* __restrict__ Wc, int C) {
  int i = blockIdx.x * 256 + threadIdx.x;  // 16384
  int r = i >> 7, k = i & 127;
  float v = 0.f;
  if (r < C) v = Wl2[r * 128 + k];
  else if (r >= 64 && r < 64 + C) v = Wr2[(r - 64) * 128 + k];
  Wc[i] = f2bf(v);
}

// ---------------- bucketed CSR build ----------------

__global__ __launch_bounds__(256) void k_bucket_hist(const int* __restrict__ dst, int E, int* __restrict__ bcnt) {
  __shared__ int h[NBUCKETS];
  for (int i = threadIdx.x; i < NBUCKETS; i += 256) h[i] = 0;
  __syncthreads();
  for (int i = blockIdx.x * 256 + threadIdx.x; i < E; i += gridDim.x * 256)
    atomicAdd(&h[dst[i] >> 10], 1);
  __syncthreads();
  for (int i = threadIdx.x; i < NBUCKETS; i += 256)
    if (h[i]) atomicAdd(&bcnt[i], h[i]);
}

__global__ __launch_bounds__(128) void k_bucket_scan(const int* __restrict__ bcnt, int* __restrict__ brp,
                                                     int* __restrict__ bcur) {
  __shared__ int sh[NBUCKETS];
  int tid = threadIdx.x;
  int v = bcnt[tid];
  sh[tid] = v;
  __syncthreads();
  for (int off = 1; off < NBUCKETS; off <<= 1) {
    int t = (tid >= off) ? sh[tid - off] : 0;
    __syncthreads();
    sh[tid] += t;
    __syncthreads();
  }
  int ex = sh[tid] - v;
  brp[tid] = ex;
  bcur[tid] = ex;
  if (tid == NBUCKETS - 1) brp[NBUCKETS] = sh[tid];
}

// bin edges into bucket-segmented (dst,src) pair array
__global__ __launch_bounds__(256) void k_binscatter(const int* __restrict__ dst, const int* __restrict__ src, int E,
                                                    int* __restrict__ bcur, int2* __restrict__ ebuf) {
  __shared__ int h[NBUCKETS];
  __shared__ int base[NBUCKETS];
  __shared__ int cur[NBUCKETS];
  const int e0 = blockIdx.x * 8192;
  const int e1 = min(e0 + 8192, E);
  for (int i = threadIdx.x; i < NBUCKETS; i += 256) h[i] = 0;
  __syncthreads();
  for (int e = e0 + threadIdx.x; e < e1; e += 256) atomicAdd(&h[dst[e] >> 10], 1);
  __syncthreads();
  if (threadIdx.x < NBUCKETS) {
    base[threadIdx.x] = atomicAdd(&bcur[threadIdx.x], h[threadIdx.x]);
    cur[threadIdx.x] = 0;
  }
  __syncthreads();
  for (int e = e0 + threadIdx.x; e < e1; e += 256) {
    int d = dst[e];
    int b = d >> 10;
    int pos = base[b] + atomicAdd(&cur[b], 1);
    ebuf[pos] = make_int2(d, src[e]);
  }
}

// per-bucket: node counts, LDS scan, rp/deg_inv, scatter src into csr (all atomics in LDS)
__global__ __launch_bounds__(512) void k_bucket_build(const int2* __restrict__ ebuf, const int* __restrict__ brp,
                                                      int* __restrict__ rp, float* __restrict__ deg_inv,
                                                      int* __restrict__ csr, int N, int E) {
  __shared__ int cnt[1024];
  __shared__ int pre[1024];
  __shared__ int tmp[1024];
  const int blk = blockIdx.x, tid = threadIdx.x;
  const int base = blk << 10;
  const int p0 = brp[blk], p1 = brp[blk + 1];
  for (int i = tid; i < 1024; i += 512) cnt[i] = 0;
  __syncthreads();
  for (int p = p0 + tid; p < p1; p += 512) atomicAdd(&cnt[ebuf[p].x - base], 1);
  __syncthreads();
  for (int i = tid; i < 1024; i += 512) pre[i] = cnt[i];
  __syncthreads();
  for (int off = 1; off < 1024; off <<= 1) {
    for (int i = tid; i < 1024; i += 512) tmp[i] = (i >= off) ? pre[i - off] : 0;
    __syncthreads();
    for (int i = tid; i < 1024; i += 512) pre[i] += tmp[i];
    __syncthreads();
  }
  for (int i = tid; i < 1024; i += 512) {
    int node = base + i;
    if (node < N) {
      int ex = pre[i] - cnt[i];
      rp[node] = p0 + ex;
      deg_inv[node] = 1.0f / (float)max(cnt[i], 1);
    }
    tmp[i] = pre[i] - cnt[i];  // scatter cursor
  }
  if (tid == 0 && blk == gridDim.x - 1) rp[N] = E;
  __syncthreads();
  for (int p = p0 + tid; p < p1; p += 512) {
    int2 pr = ebuf[p];
    int pos = p0 + atomicAdd(&tmp[pr.x - base], 1);
    csr[pos] = pr.y;
  }
}

// ---------------- aggregation (bf16 rows, fp32 accumulate) ----------------

__global__ __launch_bounds__(256) void k_agg128(const ushort* __restrict__ X, const int* __restrict__ rp,
                                                const int* __restrict__ csr, const float* __restrict__ deg_inv,
                                                ushort* __restrict__ out, int N) {
  int node = blockIdx.x * 4 + (threadIdx.x >> 6);
  if (node >= N) return;
  int lane = threadIdx.x & 63;
  int start = rp[node];
  int c = rp[node + 1] - start;
  const uint* X32 = reinterpret_cast<const uint*>(X);
  float ax = 0.f, ay = 0.f;
  int p = 0;
  for (; p + 3 < c; p += 4) {
    int s0 = csr[start + p];
    int s1 = csr[start + p + 1];
    int s2 = csr[start + p + 2];
    int s3 = csr[start + p + 3];
    uint v0 = X32[(size_t)s0 * 64 + lane];
    uint v1 = X32[(size_t)s1 * 64 + lane];
    uint v2 = X32[(size_t)s2 * 64 + lane];
    uint v3 = X32[(size_t)s3 * 64 + lane];
    ax += (bf2f_lo(v0) + bf2f_lo(v1)) + (bf2f_lo(v2) + bf2f_lo(v3));
    ay += (bf2f_hi(v0) + bf2f_hi(v1)) + (bf2f_hi(v2) + bf2f_hi(v3));
  }
  for (; p < c; ++p) {
    uint v0 = X32[(size_t)csr[start + p] * 64 + lane];
    ax += bf2f_lo(v0);
    ay += bf2f_hi(v0);
  }
  float di = deg_inv[node];
  uint o = (uint)f2bf(ax * di) | ((uint)f2bf(ay * di) << 16);
  reinterpret_cast<uint*>(out)[(size_t)node * 64 + lane] = o;
}

// ---------------- MFMA dual GEMM: Z = A@WA^T + B@WB^T (bias absorbed by BN) ----------------
// 64 rows/block, 4 waves x 16-row strips, K=256 combined, fragments direct from global.
// A-frag: lane holds A[row=lane&15][k = 8*(lane>>4)+j]; W row-major [F][K] is B^T.
// D: col=lane&15, row=4*(lane>>4)+r.

__global__ __launch_bounds__(256) void k_gemm_dual(const ushort* __restrict__ A, const ushort* __restrict__ B,
                                                   const ushort* __restrict__ WA, const ushort* __restrict__ WB,
                                                   float* __restrict__ partial, ushort* __restrict__ Z, int M) {
  const int tid = threadIdx.x;
  const int wave = tid >> 6, lane = tid & 63;
  const int rfrag = lane & 15, kgrp = lane >> 4;
  const int row0 = blockIdx.x * 64 + wave * 16;
  const int arow = min(row0 + rfrag, M - 1);

  f32x4 acc[8];
#pragma unroll
  for (int i = 0; i < 8; ++i) acc[i] = (f32x4){0.f, 0.f, 0.f, 0.f};

  const short8* Ap  = reinterpret_cast<const short8*>(A + (size_t)arow * 128 + kgrp * 8);
  const short8* Bp  = reinterpret_cast<const short8*>(B + (size_t)arow * 128 + kgrp * 8);
  const short8* WAp = reinterpret_cast<const short8*>(WA + rfrag * 128 + kgrp * 8);
  const short8* WBp = reinterpret_cast<const short8*>(WB + rfrag * 128 + kgrp * 8);
#pragma unroll
  for (int s = 0; s < 4; ++s) {
    short8 a = Ap[s * 4];
#pragma unroll
    for (int ft = 0; ft < 8; ++ft)
      acc[ft] = __builtin_amdgcn_mfma_f32_16x16x32_bf16(a, WAp[ft * 256 + s * 4], acc[ft], 0, 0, 0);
  }
#pragma unroll
  for (int s = 0; s < 4; ++s) {
    short8 b = Bp[s * 4];
#pragma unroll
    for (int ft = 0; ft < 8; ++ft)
      acc[ft] = __builtin_amdgcn_mfma_f32_16x16x32_bf16(b, WBp[ft * 256 + s * 4], acc[ft], 0, 0, 0);
  }

  // epilogue: bf16 store + per-block BN partial sums (from pre-rounding fp32)
  __shared__ float red[2][4][128];
  const int rbase = row0 + kgrp * 4;
#pragma unroll
  for (int ft = 0; ft < 8; ++ft) {
    float s1 = 0.f, s2 = 0.f;
#pragma unroll
    for (int r = 0; r < 4; ++r) {
      if (rbase + r < M) {
        float v = acc[ft][r];
        s1 += v;
        s2 = fmaf(v, v, s2);
        Z[(size_t)(rbase + r) * 128 + ft * 16 + rfrag] = f2bf(v);
      }
    }
    s1 += __shfl_xor(s1, 16); s2 += __shfl_xor(s2, 16);
    s1 += __shfl_xor(s1, 32); s2 += __shfl_xor(s2, 32);
    if (kgrp == 0) {
      red[0][wave][ft * 16 + rfrag] = s1;
      red[1][wave][ft * 16 + rfrag] = s2;
    }
  }
  __syncthreads();
  if (tid < 128)
    partial[(size_t)blockIdx.x * 256 + tid] =
        red[0][0][tid] + red[0][1][tid] + red[0][2][tid] + red[0][3][tid];
  else {
    int f = tid - 128;
    partial[(size_t)blockIdx.x * 256 + 128 + f] =
        red[1][0][f] + red[1][1][f] + red[1][2][f] + red[1][3][f];
  }
}

// ---------------- MFMA single GEMM (layer 2): Z = H@Wc^T ----------------

__global__ __launch_bounds__(256) void k_gemm_single(const ushort* __restrict__ H, const ushort* __restrict__ Wc,
                                                     ushort* __restrict__ Z, int M) {
  const int tid = threadIdx.x;
  const int wave = tid >> 6, lane = tid & 63;
  const int rfrag = lane & 15, kgrp = lane >> 4;
  const int row0 = blockIdx.x * 64 + wave * 16;
  const int arow = min(row0 + rfrag, M - 1);

  f32x4 acc[8];
#pragma unroll
  for (int i = 0; i < 8; ++i) acc[i] = (f32x4){0.f, 0.f, 0.f, 0.f};

  const short8* Ap = reinterpret_cast<const short8*>(H + (size_t)arow * 128 + kgrp * 8);
  const short8* Wp = reinterpret_cast<const short8*>(Wc + rfrag * 128 + kgrp * 8);
#pragma unroll
  for (int s = 0; s < 4; ++s) {
    short8 a = Ap[s * 4];
#pragma unroll
    for (int ft = 0; ft < 8; ++ft)
      acc[ft] = __builtin_amdgcn_mfma_f32_16x16x32_bf16(a, Wp[ft * 256 + s * 4], acc[ft], 0, 0, 0);
  }
  const int rbase = row0 + kgrp * 4;
#pragma unroll
  for (int ft = 0; ft < 8; ++ft) {
#pragma unroll
    for (int r = 0; r < 4; ++r) {
      if (rbase + r < M)
        Z[(size_t)(rbase + r) * 128 + ft * 16 + rfrag] = f2bf(acc[ft][r]);
    }
  }
}

// ---------------- BN reduce / finalize / apply ----------------

__global__ __launch_bounds__(256) void k_bn_reduce(const float* __restrict__ partial, int nblk,
                                                   float* __restrict__ stats) {
  float acc = 0.f;
  for (int b = blockIdx.x; b < nblk; b += gridDim.x) acc += partial[(size_t)b * 256 + threadIdx.x];
  atomicAdd(&stats[threadIdx.x], acc);
}

__global__ __launch_bounds__(128) void k_bn_finalize(const float* __restrict__ sums, const float* __restrict__ g,
                                                     const float* __restrict__ b, int M, float* __restrict__ ss) {
  int f = threadIdx.x;
  float inv = 1.0f / (float)M;
  float mean = sums[f] * inv;
  float var = sums[128 + f] * inv - mean * mean;
  var = fmaxf(var, 0.f);
  float sc = g[f] * rsqrtf(var + BN_EPS);
  ss[f] = sc;
  ss[128 + f] = fmaf(-mean, sc, b[f]);
}

__global__ __launch_bounds__(256) void k_bn_relu(uint* __restrict__ Z, int n2, const float* __restrict__ ss) {
  for (int i = blockIdx.x * 256 + threadIdx.x; i < n2; i += gridDim.x * 256) {
    uint v = Z[i];
    int f0 = (i & 63) * 2;
    float lo = fmaxf(fmaf(bf2f_lo(v), ss[f0], ss[128 + f0]), 0.f);
    float hi = fmaxf(fmaf(bf2f_hi(v), ss[f0 + 1], ss[128 + f0 + 1]), 0.f);
    Z[i] = (uint)f2bf(lo) | ((uint)f2bf(hi) << 16);
  }
}

// ---------------- layer-2 aggregation: out = mean(Y) + R + bias (fp32 out) ----------------
// Z rows: cols 0..C-1 = Y, cols 64..64+C-1 = R

__global__ __launch_bounds__(256) void k_agg47(const ushort* __restrict__ Z, const float* __restrict__ bias,
                                               const int* __restrict__ rp, const int* __restrict__ csr,
                                               const float* __restrict__ deg_inv, float* __restrict__ out,
                                               int N, int C) {
  int node = blockIdx.x * 4 + (threadIdx.x >> 6);
  int lane = threadIdx.x & 63;
  if (node >= N) return;
  int start = rp[node];
  int c = rp[node + 1] - start;
  if (lane < C) {
    float acc = 0.f;
    int p = 0;
    for (; p + 1 < c; p += 2) {
      int s0 = csr[start + p];
      int s1 = csr[start + p + 1];
      acc += bf2f(Z[(size_t)s0 * 128 + lane]) + bf2f(Z[(size_t)s1 * 128 + lane]);
    }
    if (p < c) acc += bf2f(Z[(size_t)csr[start + p] * 128 + lane]);
    float self = bf2f(Z[(size_t)node * 128 + 64 + lane]);
    out[(size_t)node * C + lane] = fmaf(acc, deg_inv[node], self + bias[lane]);
  }
}

// ---------------- host launch ----------------

extern "C" void kernel_launch(void* const* d_in, const int* in_sizes, int n_in,
                              void* d_out, int out_size, void* d_ws, size_t ws_size,
                              hipStream_t stream) {
  const float* x   = (const float*)d_in[0];
  const int*   ei  = (const int*)d_in[1];
  const float* Wl0 = (const float*)d_in[2];
  const float* Wr0 = (const float*)d_in[4];
  const float* g0  = (const float*)d_in[5];
  const float* b0  = (const float*)d_in[6];
  const float* Wl1 = (const float*)d_in[7];
  const float* Wr1 = (const float*)d_in[9];
  const float* g1  = (const float*)d_in[10];
  const float* b1  = (const float*)d_in[11];
  const float* Wl2 = (const float*)d_in[12];
  const float* bl2 = (const float*)d_in[13];
  const float* Wr2 = (const float*)d_in[14];

  const int N = in_sizes[0] / 128;
  const int E = in_sizes[1] / 2;
  const int C = in_sizes[13];  // 47

  const int* edst = ei;
  const int* esrc = ei + E;

  char* w = (char*)d_ws;
  auto al = [](size_t v) { return (v + 255) & ~(size_t)255; };
  size_t off = 0;
  int*    bcnt    = (int*)(w + off);    off = al(off + NBUCKETS * 4);
  int*    brp     = (int*)(w + off);    off = al(off + (NBUCKETS + 1) * 4);
  int*    bcur    = (int*)(w + off);    off = al(off + NBUCKETS * 4);
  float*  stats   = (float*)(w + off);  off = al(off + 512 * 4);       // sums[256] + ss[256]
  int*    rp      = (int*)(w + off);    off = al(off + (size_t)(N + 1) * 4);
  float*  deg_inv = (float*)(w + off);  off = al(off + (size_t)N * 4);
  int*    csr     = (int*)(w + off);    off = al(off + (size_t)E * 4);
  int2*   ebuf    = (int2*)(w + off);   off = al(off + (size_t)E * 8);
  ushort* Xb      = (ushort*)(w + off); off = al(off + (size_t)N * 128 * 2);
  ushort* hA      = (ushort*)(w + off); off = al(off + (size_t)N * 128 * 2);
  ushort* hB      = (ushort*)(w + off); off = al(off + (size_t)N * 128 * 2);
  ushort* W0l     = (ushort*)(w + off); off = al(off + 16384 * 2);
  ushort* W0r     = (ushort*)(w + off); off = al(off + 16384 * 2);
  ushort* W1l     = (ushort*)(w + off); off = al(off + 16384 * 2);
  ushort* W1r     = (ushort*)(w + off); off = al(off + 16384 * 2);
  ushort* Wc      = (ushort*)(w + off); off = al(off + 16384 * 2);
  const int nblkG = (N + 63) / 64;
  float*  partial = (float*)(w + off);  off = al(off + (size_t)nblkG * 256 * 4);

  const int aggGrid = (N + 3) / 4;
  const int nbBuck = (N + 1023) / 1024;
  const int binGrid = (E + 8191) / 8192;

  // casts
  k_cast<<<2048, 256, 0, stream>>>(x, Xb, N * 32);
  k_cast<<<16, 256, 0, stream>>>(Wl0, W0l, 4096);
  k_cast<<<16, 256, 0, stream>>>(Wr0, W0r, 4096);
  k_cast<<<16, 256, 0, stream>>>(Wl1, W1l, 4096);
  k_cast<<<16, 256, 0, stream>>>(Wr1, W1r, 4096);
  k_prep_w2<<<64, 256, 0, stream>>>(Wl2, Wr2, Wc, C);

  // bucketed CSR build
  hipMemsetAsync(bcnt, 0, NBUCKETS * 4, stream);
  k_bucket_hist<<<256, 256, 0, stream>>>(edst, E, bcnt);
  k_bucket_scan<<<1, 128, 0, stream>>>(bcnt, brp, bcur);
  k_binscatter<<<binGrid, 256, 0, stream>>>(edst, esrc, E, bcur, ebuf);
  k_bucket_build<<<nbBuck, 512, 0, stream>>>(ebuf, brp, rp, deg_inv, csr, N, E);

  // Layer 0
  k_agg128<<<aggGrid, 256, 0, stream>>>(Xb, rp, csr, deg_inv, hA, N);
  k_gemm_dual<<<nblkG, 256, 0, stream>>>(hA, Xb, W0l, W0r, partial, hB, N);
  hipMemsetAsync(stats, 0, 256 * 4, stream);
  k_bn_reduce<<<64, 256, 0, stream>>>(partial, nblkG, stats);
  k_bn_finalize<<<1, 128, 0, stream>>>(stats, g0, b0, N, stats + 256);
  k_bn_relu<<<2048, 256, 0, stream>>>((uint*)hB, N * 64, stats + 256);

  // Layer 1 (in-place GEMM into hB: each wave reads only its own rows before epilogue)
  k_agg128<<<aggGrid, 256, 0, stream>>>(hB, rp, csr, deg_inv, hA, N);
  k_gemm_dual<<<nblkG, 256, 0, stream>>>(hA, hB, W1l, W1r, partial, hB, N);
  hipMemsetAsync(stats, 0, 256 * 4, stream);
  k_bn_reduce<<<64, 256, 0, stream>>>(partial, nblkG, stats);
  k_bn_finalize<<<1, 128, 0, stream>>>(stats, g1, b1, N, stats + 256);
  k_bn_relu<<<2048, 256, 0, stream>>>((uint*)hB, N * 64, stats + 256);

  // Layer 2: transform first (mean is linear), then aggregate in C-dim space
  k_gemm_single<<<nblkG, 256, 0, stream>>>(hB, Wc, hA, N);
  k_agg47<<<aggGrid, 256, 0, stream>>>(hA, bl2, rp, csr, deg_inv, (float*)d_out, N, C);
}

// Round 4
// 461.625 us; speedup vs baseline: 4.2149x; 1.1577x over previous
//
#include <hip/hip_runtime.h>

typedef __attribute__((ext_vector_type(8))) short short8;
typedef __attribute__((ext_vector_type(4))) float f32x4;

constexpr float BN_EPS = 1e-5f;
#define NBUCKETS 128  // buckets of 1024 nodes; N <= 131072

__device__ __forceinline__ ushort f2bf(float f) {
  uint u = __float_as_uint(f);
  u = (u + 0x7fffu + ((u >> 16) & 1u)) >> 16;
  return (ushort)u;
}
__device__ __forceinline__ float bf2f(ushort h) { return __uint_as_float((uint)h << 16); }
__device__ __forceinline__ float bf2f_lo(uint v) { return __uint_as_float(v << 16); }
__device__ __forceinline__ float bf2f_hi(uint v) { return __uint_as_float(v & 0xffff0000u); }

// ---------------- fp32 -> bf16 cast (x) ----------------

__global__ __launch_bounds__(256) void k_cast(const float* __restrict__ in, ushort* __restrict__ out, int n4) {
  for (int i = blockIdx.x * 256 + threadIdx.x; i < n4; i += gridDim.x * 256) {
    float4 v = reinterpret_cast<const float4*>(in)[i];
    ushort4 o;
    o.x = f2bf(v.x); o.y = f2bf(v.y); o.z = f2bf(v.z); o.w = f2bf(v.w);
    reinterpret_cast<ushort4*>(out)[i] = o;
  }
}

// all weight preps in one launch: blocks 0-63 cast the 4 128x128 weights,
// blocks 64-127 build the packed layer-2 weight (rows 0..C-1=Wl2, 64..64+C-1=Wr2)
__global__ __launch_bounds__(256) void k_prep_weights(const float* __restrict__ Wl0, const float* __restrict__ Wr0,
                                                      const float* __restrict__ Wl1, const float* __restrict__ Wr1,
                                                      const float* __restrict__ Wl2, const float* __restrict__ Wr2,
                                                      ushort* __restrict__ W0l, ushort* __restrict__ W0r,
                                                      ushort* __restrict__ W1l, ushort* __restrict__ W1r,
                                                      ushort* __restrict__ Wc, int C) {
  int b = blockIdx.x;
  if (b < 64) {
    const float* src = (b < 16) ? Wl0 : (b < 32) ? Wr0 : (b < 48) ? Wl1 : Wr1;
    ushort* dst = (b < 16) ? W0l : (b < 32) ? W0r : (b < 48) ? W1l : W1r;
    int i = (b & 15) * 256 + threadIdx.x;  // 4096 float4 per matrix
    float4 v = reinterpret_cast<const float4*>(src)[i];
    ushort4 o;
    o.x = f2bf(v.x); o.y = f2bf(v.y); o.z = f2bf(v.z); o.w = f2bf(v.w);
    reinterpret_cast<ushort4*>(dst)[i] = o;
  } else {
    int i = (b - 64) * 256 + threadIdx.x;  // 16384
    int r = i >> 7, k = i & 127;
    float v = 0.f;
    if (r < C) v = Wl2[r * 128 + k];
    else if (r >= 64 && r < 64 + C) v = Wr2[(r - 64) * 128 + k];
    Wc[i] = f2bf(v);
  }
}

// ---------------- bucketed CSR build ----------------

__global__ __launch_bounds__(256) void k_bucket_hist(const int* __restrict__ dst, int E, int* __restrict__ bcnt) {
  __shared__ int h[NBUCKETS];
  for (int i = threadIdx.x; i < NBUCKETS; i += 256) h[i] = 0;
  __syncthreads();
  for (int i = blockIdx.x * 256 + threadIdx.x; i < E; i += gridDim.x * 256)
    atomicAdd(&h[dst[i] >> 10], 1);
  __syncthreads();
  for (int i = threadIdx.x; i < NBUCKETS; i += 256)
    if (h[i]) atomicAdd(&bcnt[i], h[i]);
}

__global__ __launch_bounds__(128) void k_bucket_scan(const int* __restrict__ bcnt, int* __restrict__ brp,
                                                     int* __restrict__ bcur) {
  __shared__ int sh[NBUCKETS];
  int tid = threadIdx.x;
  int v = bcnt[tid];
  sh[tid] = v;
  __syncthreads();
  for (int off = 1; off < NBUCKETS; off <<= 1) {
    int t = (tid >= off) ? sh[tid - off] : 0;
    __syncthreads();
    sh[tid] += t;
    __syncthreads();
  }
  int ex = sh[tid] - v;
  brp[tid] = ex;
  bcur[tid] = ex;
  if (tid == NBUCKETS - 1) brp[NBUCKETS] = sh[tid];
}

// bin edges into bucket-segmented (dst,src) pair array
__global__ __launch_bounds__(256) void k_binscatter(const int* __restrict__ dst, const int* __restrict__ src, int E,
                                                    int* __restrict__ bcur, int2* __restrict__ ebuf) {
  __shared__ int h[NBUCKETS];
  __shared__ int base[NBUCKETS];
  __shared__ int cur[NBUCKETS];
  const int e0 = blockIdx.x * 8192;
  const int e1 = min(e0 + 8192, E);
  for (int i = threadIdx.x; i < NBUCKETS; i += 256) h[i] = 0;
  __syncthreads();
  for (int e = e0 + threadIdx.x; e < e1; e += 256) atomicAdd(&h[dst[e] >> 10], 1);
  __syncthreads();
  if (threadIdx.x < NBUCKETS) {
    base[threadIdx.x] = atomicAdd(&bcur[threadIdx.x], h[threadIdx.x]);
    cur[threadIdx.x] = 0;
  }
  __syncthreads();
  for (int e = e0 + threadIdx.x; e < e1; e += 256) {
    int d = dst[e];
    int b = d >> 10;
    int pos = base[b] + atomicAdd(&cur[b], 1);
    ebuf[pos] = make_int2(d, src[e]);
  }
}

// per-bucket: node counts, LDS scan, rp/deg_inv, scatter src into csr (all atomics in LDS)
__global__ __launch_bounds__(512) void k_bucket_build(const int2* __restrict__ ebuf, const int* __restrict__ brp,
                                                      int* __restrict__ rp, float* __restrict__ deg_inv,
                                                      int* __restrict__ csr, int N, int E) {
  __shared__ int cnt[1024];
  __shared__ int pre[1024];
  __shared__ int tmp[1024];
  const int blk = blockIdx.x, tid = threadIdx.x;
  const int base = blk << 10;
  const int p0 = brp[blk], p1 = brp[blk + 1];
  for (int i = tid; i < 1024; i += 512) cnt[i] = 0;
  __syncthreads();
  for (int p = p0 + tid; p < p1; p += 512) atomicAdd(&cnt[ebuf[p].x - base], 1);
  __syncthreads();
  for (int i = tid; i < 1024; i += 512) pre[i] = cnt[i];
  __syncthreads();
  for (int off = 1; off < 1024; off <<= 1) {
    for (int i = tid; i < 1024; i += 512) tmp[i] = (i >= off) ? pre[i - off] : 0;
    __syncthreads();
    for (int i = tid; i < 1024; i += 512) pre[i] += tmp[i];
    __syncthreads();
  }
  for (int i = tid; i < 1024; i += 512) {
    int node = base + i;
    if (node < N) {
      int ex = pre[i] - cnt[i];
      rp[node] = p0 + ex;
      deg_inv[node] = 1.0f / (float)max(cnt[i], 1);
    }
    tmp[i] = pre[i] - cnt[i];  // scatter cursor
  }
  if (tid == 0 && blk == gridDim.x - 1) rp[N] = E;
  __syncthreads();
  for (int p = p0 + tid; p < p1; p += 512) {
    int2 pr = ebuf[p];
    int pos = p0 + atomicAdd(&tmp[pr.x - base], 1);
    csr[pos] = pr.y;
  }
}

// ---------------- aggregation (bf16 rows, fp32 accumulate, 8-deep MLP) ----------------

__global__ __launch_bounds__(256) void k_agg128(const ushort* __restrict__ X, const int* __restrict__ rp,
                                                const int* __restrict__ csr, const float* __restrict__ deg_inv,
                                                ushort* __restrict__ out, int N) {
  int node = blockIdx.x * 4 + (threadIdx.x >> 6);
  if (node >= N) return;
  int lane = threadIdx.x & 63;
  int start = rp[node];
  int c = rp[node + 1] - start;
  const uint* X32 = reinterpret_cast<const uint*>(X);
  float ax = 0.f, ay = 0.f;
  int p = 0;
  for (; p + 7 < c; p += 8) {
    int idx[8];
#pragma unroll
    for (int u = 0; u < 8; ++u) idx[u] = csr[start + p + u];
    uint v[8];
#pragma unroll
    for (int u = 0; u < 8; ++u) v[u] = X32[(size_t)idx[u] * 64 + lane];
#pragma unroll
    for (int u = 0; u < 8; ++u) { ax += bf2f_lo(v[u]); ay += bf2f_hi(v[u]); }
  }
  if (p + 3 < c) {
    int idx[4];
#pragma unroll
    for (int u = 0; u < 4; ++u) idx[u] = csr[start + p + u];
    uint v[4];
#pragma unroll
    for (int u = 0; u < 4; ++u) v[u] = X32[(size_t)idx[u] * 64 + lane];
#pragma unroll
    for (int u = 0; u < 4; ++u) { ax += bf2f_lo(v[u]); ay += bf2f_hi(v[u]); }
    p += 4;
  }
  for (; p < c; ++p) {
    uint v0 = X32[(size_t)csr[start + p] * 64 + lane];
    ax += bf2f_lo(v0);
    ay += bf2f_hi(v0);
  }
  float di = deg_inv[node];
  uint o = (uint)f2bf(ax * di) | ((uint)f2bf(ay * di) << 16);
  reinterpret_cast<uint*>(out)[(size_t)node * 64 + lane] = o;
}

// ---------------- MFMA dual GEMM: Z = A@WA^T + B@WB^T (bias absorbed by BN) ----------------
// 64 rows/block, 4 waves x 16-row strips, K=256 combined, fragments direct from global.
// A-frag: lane holds A[row=lane&15][k = 8*(lane>>4)+j]; W row-major [F][K] is B^T.
// D: col=lane&15, row=4*(lane>>4)+r.

__global__ __launch_bounds__(256) void k_gemm_dual(const ushort* __restrict__ A, const ushort* __restrict__ B,
                                                   const ushort* __restrict__ WA, const ushort* __restrict__ WB,
                                                   float* __restrict__ partial, ushort* __restrict__ Z, int M) {
  const int tid = threadIdx.x;
  const int wave = tid >> 6, lane = tid & 63;
  const int rfrag = lane & 15, kgrp = lane >> 4;
  const int row0 = blockIdx.x * 64 + wave * 16;
  const int arow = min(row0 + rfrag, M - 1);

  f32x4 acc[8];
#pragma unroll
  for (int i = 0; i < 8; ++i) acc[i] = (f32x4){0.f, 0.f, 0.f, 0.f};

  const short8* Ap  = reinterpret_cast<const short8*>(A + (size_t)arow * 128 + kgrp * 8);
  const short8* Bp  = reinterpret_cast<const short8*>(B + (size_t)arow * 128 + kgrp * 8);
  const short8* WAp = reinterpret_cast<const short8*>(WA + rfrag * 128 + kgrp * 8);
  const short8* WBp = reinterpret_cast<const short8*>(WB + rfrag * 128 + kgrp * 8);
#pragma unroll
  for (int s = 0; s < 4; ++s) {
    short8 a = Ap[s * 4];
#pragma unroll
    for (int ft = 0; ft < 8; ++ft)
      acc[ft] = __builtin_amdgcn_mfma_f32_16x16x32_bf16(a, WAp[ft * 256 + s * 4], acc[ft], 0, 0, 0);
  }
#pragma unroll
  for (int s = 0; s < 4; ++s) {
    short8 b = Bp[s * 4];
#pragma unroll
    for (int ft = 0; ft < 8; ++ft)
      acc[ft] = __builtin_amdgcn_mfma_f32_16x16x32_bf16(b, WBp[ft * 256 + s * 4], acc[ft], 0, 0, 0);
  }

  // epilogue: bf16 store + per-block BN partial sums (from pre-rounding fp32)
  __shared__ float red[2][4][128];
  const int rbase = row0 + kgrp * 4;
#pragma unroll
  for (int ft = 0; ft < 8; ++ft) {
    float s1 = 0.f, s2 = 0.f;
#pragma unroll
    for (int r = 0; r < 4; ++r) {
      if (rbase + r < M) {
        float v = acc[ft][r];
        s1 += v;
        s2 = fmaf(v, v, s2);
        Z[(size_t)(rbase + r) * 128 + ft * 16 + rfrag] = f2bf(v);
      }
    }
    s1 += __shfl_xor(s1, 16); s2 += __shfl_xor(s2, 16);
    s1 += __shfl_xor(s1, 32); s2 += __shfl_xor(s2, 32);
    if (kgrp == 0) {
      red[0][wave][ft * 16 + rfrag] = s1;
      red[1][wave][ft * 16 + rfrag] = s2;
    }
  }
  __syncthreads();
  if (tid < 128)
    partial[(size_t)blockIdx.x * 256 + tid] =
        red[0][0][tid] + red[0][1][tid] + red[0][2][tid] + red[0][3][tid];
  else {
    int f = tid - 128;
    partial[(size_t)blockIdx.x * 256 + 128 + f] =
        red[1][0][f] + red[1][1][f] + red[1][2][f] + red[1][3][f];
  }
}

// ---------------- MFMA single GEMM (layer 2): Z = H@Wc^T ----------------
// only 6 of 8 column tiles are nonzero (cols 0..47 = Y, 64..111 = R)

__global__ __launch_bounds__(256) void k_gemm_single(const ushort* __restrict__ H, const ushort* __restrict__ Wc,
                                                     ushort* __restrict__ Z, int M) {
  const int tid = threadIdx.x;
  const int wave = tid >> 6, lane = tid & 63;
  const int rfrag = lane & 15, kgrp = lane >> 4;
  const int row0 = blockIdx.x * 64 + wave * 16;
  const int arow = min(row0 + rfrag, M - 1);
  const int ftmap[6] = {0, 1, 2, 4, 5, 6};

  f32x4 acc[6];
#pragma unroll
  for (int i = 0; i < 6; ++i) acc[i] = (f32x4){0.f, 0.f, 0.f, 0.f};

  const short8* Ap = reinterpret_cast<const short8*>(H + (size_t)arow * 128 + kgrp * 8);
  const short8* Wp = reinterpret_cast<const short8*>(Wc + rfrag * 128 + kgrp * 8);
#pragma unroll
  for (int s = 0; s < 4; ++s) {
    short8 a = Ap[s * 4];
#pragma unroll
    for (int t = 0; t < 6; ++t)
      acc[t] = __builtin_amdgcn_mfma_f32_16x16x32_bf16(a, Wp[ftmap[t] * 256 + s * 4], acc[t], 0, 0, 0);
  }
  const int rbase = row0 + kgrp * 4;
#pragma unroll
  for (int t = 0; t < 6; ++t) {
#pragma unroll
    for (int r = 0; r < 4; ++r) {
      if (rbase + r < M)
        Z[(size_t)(rbase + r) * 128 + ftmap[t] * 16 + rfrag] = f2bf(acc[t][r]);
    }
  }
}

// ---------------- BN reduce / finalize / apply ----------------

__global__ __launch_bounds__(256) void k_bn_reduce(const float* __restrict__ partial, int nblk,
                                                   float* __restrict__ stats) {
  float acc = 0.f;
  for (int b = blockIdx.x; b < nblk; b += gridDim.x) acc += partial[(size_t)b * 256 + threadIdx.x];
  atomicAdd(&stats[threadIdx.x], acc);
}

__global__ __launch_bounds__(128) void k_bn_finalize(const float* __restrict__ sums, const float* __restrict__ g,
                                                     const float* __restrict__ b, int M, float* __restrict__ ss) {
  int f = threadIdx.x;
  float inv = 1.0f / (float)M;
  float mean = sums[f] * inv;
  float var = sums[128 + f] * inv - mean * mean;
  var = fmaxf(var, 0.f);
  float sc = g[f] * rsqrtf(var + BN_EPS);
  ss[f] = sc;
  ss[128 + f] = fmaf(-mean, sc, b[f]);
}

__global__ __launch_bounds__(256) void k_bn_relu(uint2* __restrict__ Z, int n2, const float* __restrict__ ss) {
  for (int i = blockIdx.x * 256 + threadIdx.x; i < n2; i += gridDim.x * 256) {
    uint2 v = Z[i];
    int f0 = (i & 31) * 4;
    float4 sc = *reinterpret_cast<const float4*>(&ss[f0]);
    float4 sh = *reinterpret_cast<const float4*>(&ss[128 + f0]);
    float a0 = fmaxf(fmaf(bf2f_lo(v.x), sc.x, sh.x), 0.f);
    float a1 = fmaxf(fmaf(bf2f_hi(v.x), sc.y, sh.y), 0.f);
    float a2 = fmaxf(fmaf(bf2f_lo(v.y), sc.z, sh.z), 0.f);
    float a3 = fmaxf(fmaf(bf2f_hi(v.y), sc.w, sh.w), 0.f);
    v.x = (uint)f2bf(a0) | ((uint)f2bf(a1) << 16);
    v.y = (uint)f2bf(a2) | ((uint)f2bf(a3) << 16);
    Z[i] = v;
  }
}

// ---------------- layer-2 aggregation: out = mean(Y) + R + bias (fp32 out) ----------------
// Z rows: cols 0..C-1 = Y, cols 64..64+C-1 = R

__global__ __launch_bounds__(256) void k_agg47(const ushort* __restrict__ Z, const float* __restrict__ bias,
                                               const int* __restrict__ rp, const int* __restrict__ csr,
                                               const float* __restrict__ deg_inv, float* __restrict__ out,
                                               int N, int C) {
  int node = blockIdx.x * 4 + (threadIdx.x >> 6);
  int lane = threadIdx.x & 63;
  if (node >= N) return;
  int start = rp[node];
  int c = rp[node + 1] - start;
  if (lane < C) {
    float acc = 0.f;
    int p = 0;
    for (; p + 7 < c; p += 8) {
      int idx[8];
#pragma unroll
      for (int u = 0; u < 8; ++u) idx[u] = csr[start + p + u];
      ushort v[8];
#pragma unroll
      for (int u = 0; u < 8; ++u) v[u] = Z[(size_t)idx[u] * 128 + lane];
#pragma unroll
      for (int u = 0; u < 8; ++u) acc += bf2f(v[u]);
    }
    if (p + 3 < c) {
      int idx[4];
#pragma unroll
      for (int u = 0; u < 4; ++u) idx[u] = csr[start + p + u];
      ushort v[4];
#pragma unroll
      for (int u = 0; u < 4; ++u) v[u] = Z[(size_t)idx[u] * 128 + lane];
#pragma unroll
      for (int u = 0; u < 4; ++u) acc += bf2f(v[u]);
      p += 4;
    }
    for (; p < c; ++p) acc += bf2f(Z[(size_t)csr[start + p] * 128 + lane]);
    float self = bf2f(Z[(size_t)node * 128 + 64 + lane]);
    out[(size_t)node * C + lane] = fmaf(acc, deg_inv[node], self + bias[lane]);
  }
}

// ---------------- host launch ----------------

extern "C" void kernel_launch(void* const* d_in, const int* in_sizes, int n_in,
                              void* d_out, int out_size, void* d_ws, size_t ws_size,
                              hipStream_t stream) {
  const float* x   = (const float*)d_in[0];
  const int*   ei  = (const int*)d_in[1];
  const float* Wl0 = (const float*)d_in[2];
  const float* Wr0 = (const float*)d_in[4];
  const float* g0  = (const float*)d_in[5];
  const float* b0  = (const float*)d_in[6];
  const float* Wl1 = (const float*)d_in[7];
  const float* Wr1 = (const float*)d_in[9];
  const float* g1  = (const float*)d_in[10];
  const float* b1  = (const float*)d_in[11];
  const float* Wl2 = (const float*)d_in[12];
  const float* bl2 = (const float*)d_in[13];
  const float* Wr2 = (const float*)d_in[14];

  const int N = in_sizes[0] / 128;
  const int E = in_sizes[1] / 2;
  const int C = in_sizes[13];  // 47

  const int* edst = ei;
  const int* esrc = ei + E;

  char* w = (char*)d_ws;
  auto al = [](size_t v) { return (v + 255) & ~(size_t)255; };
  size_t off = 0;
  int*    bcnt    = (int*)(w + off);    off = al(off + NBUCKETS * 4);
  int*    brp     = (int*)(w + off);    off = al(off + (NBUCKETS + 1) * 4);
  int*    bcur    = (int*)(w + off);    off = al(off + NBUCKETS * 4);
  float*  stats   = (float*)(w + off);  off = al(off + 512 * 4);       // sums[256] + ss[256]
  int*    rp      = (int*)(w + off);    off = al(off + (size_t)(N + 1) * 4);
  float*  deg_inv = (float*)(w + off);  off = al(off + (size_t)N * 4);
  int*    csr     = (int*)(w + off);    off = al(off + (size_t)E * 4);
  int2*   ebuf    = (int2*)(w + off);   off = al(off + (size_t)E * 8);
  ushort* Xb      = (ushort*)(w + off); off = al(off + (size_t)N * 128 * 2);
  ushort* hA      = (ushort*)(w + off); off = al(off + (size_t)N * 128 * 2);
  ushort* hB      = (ushort*)(w + off); off = al(off + (size_t)N * 128 * 2);
  ushort* W0l     = (ushort*)(w + off); off = al(off + 16384 * 2);
  ushort* W0r     = (ushort*)(w + off); off = al(off + 16384 * 2);
  ushort* W1l     = (ushort*)(w + off); off = al(off + 16384 * 2);
  ushort* W1r     = (ushort*)(w + off); off = al(off + 16384 * 2);
  ushort* Wc      = (ushort*)(w + off); off = al(off + 16384 * 2);
  const int nblkG = (N + 63) / 64;
  float*  partial = (float*)(w + off);  off = al(off + (size_t)nblkG * 256 * 4);

  const int aggGrid = (N + 3) / 4;
  const int nbBuck = (N + 1023) / 1024;
  const int binGrid = (E + 8191) / 8192;

  // casts + weight prep (single launch for all weights)
  k_cast<<<2048, 256, 0, stream>>>(x, Xb, N * 32);
  k_prep_weights<<<128, 256, 0, stream>>>(Wl0, Wr0, Wl1, Wr1, Wl2, Wr2, W0l, W0r, W1l, W1r, Wc, C);

  // bucketed CSR build
  hipMemsetAsync(bcnt, 0, NBUCKETS * 4, stream);
  k_bucket_hist<<<256, 256, 0, stream>>>(edst, E, bcnt);
  k_bucket_scan<<<1, 128, 0, stream>>>(bcnt, brp, bcur);
  k_binscatter<<<binGrid, 256, 0, stream>>>(edst, esrc, E, bcur, ebuf);
  k_bucket_build<<<nbBuck, 512, 0, stream>>>(ebuf, brp, rp, deg_inv, csr, N, E);

  // Layer 0
  k_agg128<<<aggGrid, 256, 0, stream>>>(Xb, rp, csr, deg_inv, hA, N);
  k_gemm_dual<<<nblkG, 256, 0, stream>>>(hA, Xb, W0l, W0r, partial, hB, N);
  hipMemsetAsync(stats, 0, 256 * 4, stream);
  k_bn_reduce<<<64, 256, 0, stream>>>(partial, nblkG, stats);
  k_bn_finalize<<<1, 128, 0, stream>>>(stats, g0, b0, N, stats + 256);
  k_bn_relu<<<2048, 256, 0, stream>>>((uint2*)hB, N * 32, stats + 256);

  // Layer 1 (in-place GEMM into hB: each wave reads only its own rows before epilogue)
  k_agg128<<<aggGrid, 256, 0, stream>>>(hB, rp, csr, deg_inv, hA, N);
  k_gemm_dual<<<nblkG, 256, 0, stream>>>(hA, hB, W1l, W1r, partial, hB, N);
  hipMemsetAsync(stats, 0, 256 * 4, stream);
  k_bn_reduce<<<64, 256, 0, stream>>>(partial, nblkG, stats);
  k_bn_finalize<<<1, 128, 0, stream>>>(stats, g1, b1, N, stats + 256);
  k_bn_relu<<<2048, 256, 0, stream>>>((uint2*)hB, N * 32, stats + 256);

  // Layer 2: transform first (mean is linear), then aggregate in C-dim space
  k_gemm_single<<<nblkG, 256, 0, stream>>>(hB, Wc, hA, N);
  k_agg47<<<aggGrid, 256, 0, stream>>>(hA, bl2, rp, csr, deg_inv, (float*)d_out, N, C);
}

// Round 5
// 433.554 us; speedup vs baseline: 4.4878x; 1.0647x over previous
//
#include <hip/hip_runtime.h>

typedef __attribute__((ext_vector_type(8))) short short8;
typedef __attribute__((ext_vector_type(4))) float f32x4;

constexpr float BN_EPS = 1e-5f;
#define NBUCKETS 128  // buckets of 1024 nodes; N <= 131072

__device__ __forceinline__ ushort f2bf(float f) {
  uint u = __float_as_uint(f);
  u = (u + 0x7fffu + ((u >> 16) & 1u)) >> 16;
  return (ushort)u;
}
__device__ __forceinline__ float bf2f(ushort h) { return __uint_as_float((uint)h << 16); }
__device__ __forceinline__ float bf2f_lo(uint v) { return __uint_as_float(v << 16); }
__device__ __forceinline__ float bf2f_hi(uint v) { return __uint_as_float(v & 0xffff0000u); }

// ---------------- fp32 -> bf16 cast (x) ----------------

__global__ __launch_bounds__(256) void k_cast(const float* __restrict__ in, ushort* __restrict__ out, int n4) {
  for (int i = blockIdx.x * 256 + threadIdx.x; i < n4; i += gridDim.x * 256) {
    float4 v = reinterpret_cast<const float4*>(in)[i];
    ushort4 o;
    o.x = f2bf(v.x); o.y = f2bf(v.y); o.z = f2bf(v.z); o.w = f2bf(v.w);
    reinterpret_cast<ushort4*>(out)[i] = o;
  }
}

// all weight preps in one launch: blocks 0-63 cast the 4 128x128 weights,
// blocks 64-127 build the packed layer-2 weight (rows 0..C-1=Wl2, 64..64+C-1=Wr2)
__global__ __launch_bounds__(256) void k_prep_weights(const float* __restrict__ Wl0, const float* __restrict__ Wr0,
                                                      const float* __restrict__ Wl1, const float* __restrict__ Wr1,
                                                      const float* __restrict__ Wl2, const float* __restrict__ Wr2,
                                                      ushort* __restrict__ W0l, ushort* __restrict__ W0r,
                                                      ushort* __restrict__ W1l, ushort* __restrict__ W1r,
                                                      ushort* __restrict__ Wc, int C) {
  int b = blockIdx.x;
  if (b < 64) {
    const float* src = (b < 16) ? Wl0 : (b < 32) ? Wr0 : (b < 48) ? Wl1 : Wr1;
    ushort* dst = (b < 16) ? W0l : (b < 32) ? W0r : (b < 48) ? W1l : W1r;
    int i = (b & 15) * 256 + threadIdx.x;  // 4096 float4 per matrix
    float4 v = reinterpret_cast<const float4*>(src)[i];
    ushort4 o;
    o.x = f2bf(v.x); o.y = f2bf(v.y); o.z = f2bf(v.z); o.w = f2bf(v.w);
    reinterpret_cast<ushort4*>(dst)[i] = o;
  } else {
    int i = (b - 64) * 256 + threadIdx.x;  // 16384
    int r = i >> 7, k = i & 127;
    float v = 0.f;
    if (r < C) v = Wl2[r * 128 + k];
    else if (r >= 64 && r < 64 + C) v = Wr2[(r - 64) * 128 + k];
    Wc[i] = f2bf(v);
  }
}

// ---------------- bucketed CSR build ----------------

__global__ __launch_bounds__(256) void k_bucket_hist(const int* __restrict__ dst, int E, int* __restrict__ bcnt) {
  __shared__ int h[NBUCKETS];
  for (int i = threadIdx.x; i < NBUCKETS; i += 256) h[i] = 0;
  __syncthreads();
  for (int i = blockIdx.x * 256 + threadIdx.x; i < E; i += gridDim.x * 256)
    atomicAdd(&h[dst[i] >> 10], 1);
  __syncthreads();
  for (int i = threadIdx.x; i < NBUCKETS; i += 256)
    if (h[i]) atomicAdd(&bcnt[i], h[i]);
}

__global__ __launch_bounds__(128) void k_bucket_scan(const int* __restrict__ bcnt, int* __restrict__ brp,
                                                     int* __restrict__ bcur) {
  __shared__ int sh[NBUCKETS];
  int tid = threadIdx.x;
  int v = bcnt[tid];
  sh[tid] = v;
  __syncthreads();
  for (int off = 1; off < NBUCKETS; off <<= 1) {
    int t = (tid >= off) ? sh[tid - off] : 0;
    __syncthreads();
    sh[tid] += t;
    __syncthreads();
  }
  int ex = sh[tid] - v;
  brp[tid] = ex;
  bcur[tid] = ex;
  if (tid == NBUCKETS - 1) brp[NBUCKETS] = sh[tid];
}

// bin edges into bucket-segmented packed array: (dst & 1023) | (src << 10)
__global__ __launch_bounds__(256) void k_binscatter(const int* __restrict__ dst, const int* __restrict__ src, int E,
                                                    int* __restrict__ bcur, uint* __restrict__ ebuf) {
  __shared__ int h[NBUCKETS];
  __shared__ int base[NBUCKETS];
  __shared__ int cur[NBUCKETS];
  const int e0 = blockIdx.x * 8192;
  const int e1 = min(e0 + 8192, E);
  for (int i = threadIdx.x; i < NBUCKETS; i += 256) h[i] = 0;
  __syncthreads();
  for (int e = e0 + threadIdx.x; e < e1; e += 256) atomicAdd(&h[dst[e] >> 10], 1);
  __syncthreads();
  if (threadIdx.x < NBUCKETS) {
    base[threadIdx.x] = atomicAdd(&bcur[threadIdx.x], h[threadIdx.x]);
    cur[threadIdx.x] = 0;
  }
  __syncthreads();
  for (int e = e0 + threadIdx.x; e < e1; e += 256) {
    int d = dst[e];
    int b = d >> 10;
    int pos = base[b] + atomicAdd(&cur[b], 1);
    ebuf[pos] = (uint)(d & 1023) | ((uint)src[e] << 10);
  }
}

// per-bucket: node counts, LDS scan, rp/deg_inv, scatter src into csr (all atomics in LDS)
__global__ __launch_bounds__(512) void k_bucket_build(const uint* __restrict__ ebuf, const int* __restrict__ brp,
                                                      int* __restrict__ rp, float* __restrict__ deg_inv,
                                                      int* __restrict__ csr, int N, int E) {
  __shared__ int cnt[1024];
  __shared__ int pre[1024];
  __shared__ int tmp[1024];
  const int blk = blockIdx.x, tid = threadIdx.x;
  const int base = blk << 10;
  const int p0 = brp[blk], p1 = brp[blk + 1];
  for (int i = tid; i < 1024; i += 512) cnt[i] = 0;
  __syncthreads();
  for (int p = p0 + tid; p < p1; p += 512) atomicAdd(&cnt[ebuf[p] & 1023u], 1);
  __syncthreads();
  for (int i = tid; i < 1024; i += 512) pre[i] = cnt[i];
  __syncthreads();
  for (int off = 1; off < 1024; off <<= 1) {
    for (int i = tid; i < 1024; i += 512) tmp[i] = (i >= off) ? pre[i - off] : 0;
    __syncthreads();
    for (int i = tid; i < 1024; i += 512) pre[i] += tmp[i];
    __syncthreads();
  }
  for (int i = tid; i < 1024; i += 512) {
    int node = base + i;
    if (node < N) {
      int ex = pre[i] - cnt[i];
      rp[node] = p0 + ex;
      deg_inv[node] = 1.0f / (float)max(cnt[i], 1);
    }
    tmp[i] = pre[i] - cnt[i];  // scatter cursor
  }
  if (tid == 0 && blk == gridDim.x - 1) rp[N] = E;
  __syncthreads();
  for (int p = p0 + tid; p < p1; p += 512) {
    uint pr = ebuf[p];
    int pos = p0 + atomicAdd(&tmp[pr & 1023u], 1);
    csr[pos] = (int)(pr >> 10);
  }
}

// ---------------- aggregation (bf16 rows; 4 nodes/wave, 16 lanes x 16B per row) ----------------

__global__ __launch_bounds__(256) void k_agg128(const ushort* __restrict__ X, const int* __restrict__ rp,
                                                const int* __restrict__ csr, const float* __restrict__ deg_inv,
                                                ushort* __restrict__ out, int N) {
  const int wave = threadIdx.x >> 6, lane = threadIdx.x & 63;
  const int sub = lane >> 4, li = lane & 15;
  const int node = blockIdx.x * 16 + wave * 4 + sub;
  if (node >= N) return;
  const int start = rp[node];
  const int c = rp[node + 1] - start;
  const uint4* X16 = reinterpret_cast<const uint4*>(X);
  float a0 = 0.f, a1 = 0.f, a2 = 0.f, a3 = 0.f, a4 = 0.f, a5 = 0.f, a6 = 0.f, a7 = 0.f;
  int p = 0;
  for (; p + 7 < c; p += 8) {
    int idx[8];
#pragma unroll
    for (int u = 0; u < 8; ++u) idx[u] = csr[start + p + u];
    uint4 v[8];
#pragma unroll
    for (int u = 0; u < 8; ++u) v[u] = X16[(size_t)idx[u] * 16 + li];
#pragma unroll
    for (int u = 0; u < 8; ++u) {
      a0 += bf2f_lo(v[u].x); a1 += bf2f_hi(v[u].x);
      a2 += bf2f_lo(v[u].y); a3 += bf2f_hi(v[u].y);
      a4 += bf2f_lo(v[u].z); a5 += bf2f_hi(v[u].z);
      a6 += bf2f_lo(v[u].w); a7 += bf2f_hi(v[u].w);
    }
  }
  if (p + 3 < c) {
    int idx[4];
#pragma unroll
    for (int u = 0; u < 4; ++u) idx[u] = csr[start + p + u];
    uint4 v[4];
#pragma unroll
    for (int u = 0; u < 4; ++u) v[u] = X16[(size_t)idx[u] * 16 + li];
#pragma unroll
    for (int u = 0; u < 4; ++u) {
      a0 += bf2f_lo(v[u].x); a1 += bf2f_hi(v[u].x);
      a2 += bf2f_lo(v[u].y); a3 += bf2f_hi(v[u].y);
      a4 += bf2f_lo(v[u].z); a5 += bf2f_hi(v[u].z);
      a6 += bf2f_lo(v[u].w); a7 += bf2f_hi(v[u].w);
    }
    p += 4;
  }
  for (; p < c; ++p) {
    uint4 v = X16[(size_t)csr[start + p] * 16 + li];
    a0 += bf2f_lo(v.x); a1 += bf2f_hi(v.x);
    a2 += bf2f_lo(v.y); a3 += bf2f_hi(v.y);
    a4 += bf2f_lo(v.z); a5 += bf2f_hi(v.z);
    a6 += bf2f_lo(v.w); a7 += bf2f_hi(v.w);
  }
  const float di = deg_inv[node];
  uint4 o;
  o.x = (uint)f2bf(a0 * di) | ((uint)f2bf(a1 * di) << 16);
  o.y = (uint)f2bf(a2 * di) | ((uint)f2bf(a3 * di) << 16);
  o.z = (uint)f2bf(a4 * di) | ((uint)f2bf(a5 * di) << 16);
  o.w = (uint)f2bf(a6 * di) | ((uint)f2bf(a7 * di) << 16);
  reinterpret_cast<uint4*>(out)[(size_t)node * 16 + li] = o;
}

// ---------------- MFMA dual GEMM v2: LDS-staged, Z = A@WA^T + B@WB^T ----------------
// 64 rows/block, 4 waves x 16-row tiles. A/B tiles staged to swizzled LDS with
// contiguous 1KB loads; fragments via ds_read_b128; Z repacked through LDS for
// contiguous dwordx4 stores. Weight frags direct from global (L1-hot).
// swizzle: LDS[row][b] holds A[row][b ^ ((row&7)<<4)] (involution both sides).

__global__ __launch_bounds__(256) void k_gemm_dual(const ushort* __restrict__ A, const ushort* __restrict__ B,
                                                   const ushort* __restrict__ WA, const ushort* __restrict__ WB,
                                                   float* __restrict__ partial, ushort* __restrict__ Z, int M) {
  __shared__ ushort sA[64 * 128];
  __shared__ ushort sB[64 * 128];
  __shared__ float red[2][4][128];
  const int tid = threadIdx.x;
  const int wave = tid >> 6, lane = tid & 63;
  const int rfrag = lane & 15, kgrp = lane >> 4;
  const int row0 = blockIdx.x * 64;

  // stage: 4 chunks of 1KB per wave per matrix (chunk = 4 rows)
#pragma unroll
  for (int it = 0; it < 4; ++it) {
    int tb = (wave * 4 + it) * 1024 + lane * 16;
    int row = tb >> 8;
    int bin = tb & 255;
    int gr = min(row0 + row, M - 1);
    uint4 va = *reinterpret_cast<const uint4*>((const char*)A + (size_t)gr * 256 + bin);
    uint4 vb = *reinterpret_cast<const uint4*>((const char*)B + (size_t)gr * 256 + bin);
    int swz = bin ^ ((row & 7) << 4);
    *reinterpret_cast<uint4*>((char*)sA + row * 256 + swz) = va;
    *reinterpret_cast<uint4*>((char*)sB + row * 256 + swz) = vb;
  }
  __syncthreads();

  // fragments from LDS
  const int r = wave * 16 + rfrag;
  const int rs = (rfrag & 7) << 4;
  short8 af[4], bf[4];
#pragma unroll
  for (int s = 0; s < 4; ++s) {
    int off = (kgrp * 16 + s * 64) ^ rs;
    af[s] = *reinterpret_cast<const short8*>((const char*)sA + r * 256 + off);
    bf[s] = *reinterpret_cast<const short8*>((const char*)sB + r * 256 + off);
  }

  f32x4 acc[8];
#pragma unroll
  for (int i = 0; i < 8; ++i) acc[i] = (f32x4){0.f, 0.f, 0.f, 0.f};

  const short8* WAp = reinterpret_cast<const short8*>(WA + rfrag * 128 + kgrp * 8);
  const short8* WBp = reinterpret_cast<const short8*>(WB + rfrag * 128 + kgrp * 8);
#pragma unroll
  for (int s = 0; s < 4; ++s) {
#pragma unroll
    for (int ft = 0; ft < 8; ++ft)
      acc[ft] = __builtin_amdgcn_mfma_f32_16x16x32_bf16(af[s], WAp[ft * 256 + s * 4], acc[ft], 0, 0, 0);
  }
#pragma unroll
  for (int s = 0; s < 4; ++s) {
#pragma unroll
    for (int ft = 0; ft < 8; ++ft)
      acc[ft] = __builtin_amdgcn_mfma_f32_16x16x32_bf16(bf[s], WBp[ft * 256 + s * 4], acc[ft], 0, 0, 0);
  }

  // BN partials from pre-rounding fp32 acc
  const int rbase = row0 + wave * 16 + kgrp * 4;
#pragma unroll
  for (int ft = 0; ft < 8; ++ft) {
    float s1 = 0.f, s2 = 0.f;
#pragma unroll
    for (int rr = 0; rr < 4; ++rr) {
      if (rbase + rr < M) {
        float v = acc[ft][rr];
        s1 += v;
        s2 = fmaf(v, v, s2);
      }
    }
    s1 += __shfl_xor(s1, 16); s2 += __shfl_xor(s2, 16);
    s1 += __shfl_xor(s1, 32); s2 += __shfl_xor(s2, 32);
    if (kgrp == 0) {
      red[0][wave][ft * 16 + rfrag] = s1;
      red[1][wave][ft * 16 + rfrag] = s2;
    }
  }
  __syncthreads();  // red complete AND all sA/sB fragment reads done

  // repack Z tile into sA (natural layout), store partials
  const int lrbase = wave * 16 + kgrp * 4;
#pragma unroll
  for (int ft = 0; ft < 8; ++ft) {
#pragma unroll
    for (int rr = 0; rr < 4; ++rr)
      sA[(lrbase + rr) * 128 + ft * 16 + rfrag] = f2bf(acc[ft][rr]);
  }
  if (tid < 128)
    partial[(size_t)blockIdx.x * 256 + tid] =
        red[0][0][tid] + red[0][1][tid] + red[0][2][tid] + red[0][3][tid];
  else {
    int f = tid - 128;
    partial[(size_t)blockIdx.x * 256 + 128 + f] =
        red[1][0][f] + red[1][1][f] + red[1][2][f] + red[1][3][f];
  }
  __syncthreads();

  // contiguous Z store
#pragma unroll
  for (int it = 0; it < 4; ++it) {
    int tb = (wave * 4 + it) * 1024 + lane * 16;
    int row = tb >> 8;
    int gr = row0 + row;
    if (gr < M)
      *reinterpret_cast<uint4*>((char*)Z + (size_t)gr * 256 + (tb & 255)) =
          *reinterpret_cast<const uint4*>((const char*)sA + tb);
  }
}

// ---------------- MFMA single GEMM v2 (layer 2): Z = H@Wc^T ----------------
// 6 of 8 col tiles nonzero; skipped tiles stored as exact zeros.

__global__ __launch_bounds__(256) void k_gemm_single(const ushort* __restrict__ H, const ushort* __restrict__ Wc,
                                                     ushort* __restrict__ Z, int M) {
  __shared__ ushort sA[64 * 128];
  const int tid = threadIdx.x;
  const int wave = tid >> 6, lane = tid & 63;
  const int rfrag = lane & 15, kgrp = lane >> 4;
  const int row0 = blockIdx.x * 64;

#pragma unroll
  for (int it = 0; it < 4; ++it) {
    int tb = (wave * 4 + it) * 1024 + lane * 16;
    int row = tb >> 8;
    int bin = tb & 255;
    int gr = min(row0 + row, M - 1);
    uint4 va = *reinterpret_cast<const uint4*>((const char*)H + (size_t)gr * 256 + bin);
    *reinterpret_cast<uint4*>((char*)sA + row * 256 + (bin ^ ((row & 7) << 4))) = va;
  }
  __syncthreads();

  const int r = wave * 16 + rfrag;
  const int rs = (rfrag & 7) << 4;
  short8 af[4];
#pragma unroll
  for (int s = 0; s < 4; ++s)
    af[s] = *reinterpret_cast<const short8*>((const char*)sA + r * 256 + ((kgrp * 16 + s * 64) ^ rs));

  f32x4 acc[8];
#pragma unroll
  for (int i = 0; i < 8; ++i) acc[i] = (f32x4){0.f, 0.f, 0.f, 0.f};
  const int ftmap[6] = {0, 1, 2, 4, 5, 6};

  const short8* Wp = reinterpret_cast<const short8*>(Wc + rfrag * 128 + kgrp * 8);
#pragma unroll
  for (int s = 0; s < 4; ++s) {
#pragma unroll
    for (int t = 0; t < 6; ++t)
      acc[ftmap[t]] = __builtin_amdgcn_mfma_f32_16x16x32_bf16(af[s], Wp[ftmap[t] * 256 + s * 4], acc[ftmap[t]], 0, 0, 0);
  }
  __syncthreads();

  const int lrbase = wave * 16 + kgrp * 4;
#pragma unroll
  for (int ft = 0; ft < 8; ++ft) {
#pragma unroll
    for (int rr = 0; rr < 4; ++rr)
      sA[(lrbase + rr) * 128 + ft * 16 + rfrag] = f2bf(acc[ft][rr]);
  }
  __syncthreads();

#pragma unroll
  for (int it = 0; it < 4; ++it) {
    int tb = (wave * 4 + it) * 1024 + lane * 16;
    int row = tb >> 8;
    int gr = row0 + row;
    if (gr < M)
      *reinterpret_cast<uint4*>((char*)Z + (size_t)gr * 256 + (tb & 255)) =
          *reinterpret_cast<const uint4*>((const char*)sA + tb);
  }
}

// ---------------- BN reduce / finalize / apply ----------------

__global__ __launch_bounds__(256) void k_bn_reduce(const float* __restrict__ partial, int nblk,
                                                   float* __restrict__ stats) {
  float acc = 0.f;
  for (int b = blockIdx.x; b < nblk; b += gridDim.x) acc += partial[(size_t)b * 256 + threadIdx.x];
  atomicAdd(&stats[threadIdx.x], acc);
}

__global__ __launch_bounds__(128) void k_bn_finalize(const float* __restrict__ sums, const float* __restrict__ g,
                                                     const float* __restrict__ b, int M, float* __restrict__ ss) {
  int f = threadIdx.x;
  float inv = 1.0f / (float)M;
  float mean = sums[f] * inv;
  float var = sums[128 + f] * inv - mean * mean;
  var = fmaxf(var, 0.f);
  float sc = g[f] * rsqrtf(var + BN_EPS);
  ss[f] = sc;
  ss[128 + f] = fmaf(-mean, sc, b[f]);
}

__global__ __launch_bounds__(256) void k_bn_relu(uint2* __restrict__ Z, int n2, const float* __restrict__ ss) {
  for (int i = blockIdx.x * 256 + threadIdx.x; i < n2; i += gridDim.x * 256) {
    uint2 v = Z[i];
    int f0 = (i & 31) * 4;
    float4 sc = *reinterpret_cast<const float4*>(&ss[f0]);
    float4 sh = *reinterpret_cast<const float4*>(&ss[128 + f0]);
    float a0 = fmaxf(fmaf(bf2f_lo(v.x), sc.x, sh.x), 0.f);
    float a1 = fmaxf(fmaf(bf2f_hi(v.x), sc.y, sh.y), 0.f);
    float a2 = fmaxf(fmaf(bf2f_lo(v.y), sc.z, sh.z), 0.f);
    float a3 = fmaxf(fmaf(bf2f_hi(v.y), sc.w, sh.w), 0.f);
    v.x = (uint)f2bf(a0) | ((uint)f2bf(a1) << 16);
    v.y = (uint)f2bf(a2) | ((uint)f2bf(a3) << 16);
    Z[i] = v;
  }
}

// ---------------- layer-2 aggregation: out = mean(Y) + R + bias (fp32 out) ----------------
// Z rows: cols 0..C-1 = Y, cols 64..64+C-1 = R; 8 nodes/wave, 8 lanes x 16B per row.

__global__ __launch_bounds__(256) void k_agg47(const ushort* __restrict__ Z, const float* __restrict__ bias,
                                               const int* __restrict__ rp, const int* __restrict__ csr,
                                               const float* __restrict__ deg_inv, float* __restrict__ out,
                                               int N, int C) {
  const int wave = threadIdx.x >> 6, lane = threadIdx.x & 63;
  const int sub = lane >> 3, li = lane & 7;
  const int node = blockIdx.x * 32 + wave * 8 + sub;
  if (node >= N) return;
  const int start = rp[node];
  const int c = rp[node + 1] - start;
  const uint4* Z16 = reinterpret_cast<const uint4*>(Z);
  float a0 = 0.f, a1 = 0.f, a2 = 0.f, a3 = 0.f, a4 = 0.f, a5 = 0.f, a6 = 0.f, a7 = 0.f;
  int p = 0;
  for (; p + 7 < c; p += 8) {
    int idx[8];
#pragma unroll
    for (int u = 0; u < 8; ++u) idx[u] = csr[start + p + u];
    uint4 v[8];
#pragma unroll
    for (int u = 0; u < 8; ++u) v[u] = Z16[(size_t)idx[u] * 16 + li];
#pragma unroll
    for (int u = 0; u < 8; ++u) {
      a0 += bf2f_lo(v[u].x); a1 += bf2f_hi(v[u].x);
      a2 += bf2f_lo(v[u].y); a3 += bf2f_hi(v[u].y);
      a4 += bf2f_lo(v[u].z); a5 += bf2f_hi(v[u].z);
      a6 += bf2f_lo(v[u].w); a7 += bf2f_hi(v[u].w);
    }
  }
  for (; p < c; ++p) {
    uint4 v = Z16[(size_t)csr[start + p] * 16 + li];
    a0 += bf2f_lo(v.x); a1 += bf2f_hi(v.x);
    a2 += bf2f_lo(v.y); a3 += bf2f_hi(v.y);
    a4 += bf2f_lo(v.z); a5 += bf2f_hi(v.z);
    a6 += bf2f_lo(v.w); a7 += bf2f_hi(v.w);
  }
  const float di = deg_inv[node];
  uint4 sv = Z16[(size_t)node * 16 + 8 + li];  // cols 64+li*8 .. +7
  float s[8] = {bf2f_lo(sv.x), bf2f_hi(sv.x), bf2f_lo(sv.y), bf2f_hi(sv.y),
                bf2f_lo(sv.z), bf2f_hi(sv.z), bf2f_lo(sv.w), bf2f_hi(sv.w)};
  float a[8] = {a0, a1, a2, a3, a4, a5, a6, a7};
#pragma unroll
  for (int j = 0; j < 8; ++j) {
    int f = li * 8 + j;
    if (f < C) out[(size_t)node * C + f] = fmaf(a[j], di, s[j] + bias[f]);
  }
}

// ---------------- host launch ----------------

extern "C" void kernel_launch(void* const* d_in, const int* in_sizes, int n_in,
                              void* d_out, int out_size, void* d_ws, size_t ws_size,
                              hipStream_t stream) {
  const float* x   = (const float*)d_in[0];
  const int*   ei  = (const int*)d_in[1];
  const float* Wl0 = (const float*)d_in[2];
  const float* Wr0 = (const float*)d_in[4];
  const float* g0  = (const float*)d_in[5];
  const float* b0  = (const float*)d_in[6];
  const float* Wl1 = (const float*)d_in[7];
  const float* Wr1 = (const float*)d_in[9];
  const float* g1  = (const float*)d_in[10];
  const float* b1  = (const float*)d_in[11];
  const float* Wl2 = (const float*)d_in[12];
  const float* bl2 = (const float*)d_in[13];
  const float* Wr2 = (const float*)d_in[14];

  const int N = in_sizes[0] / 128;
  const int E = in_sizes[1] / 2;
  const int C = in_sizes[13];  // 47

  const int* edst = ei;
  const int* esrc = ei + E;

  char* w = (char*)d_ws;
  auto al = [](size_t v) { return (v + 255) & ~(size_t)255; };
  size_t off = 0;
  int*    bcnt    = (int*)(w + off);    off = al(off + NBUCKETS * 4);
  int*    brp     = (int*)(w + off);    off = al(off + (NBUCKETS + 1) * 4);
  int*    bcur    = (int*)(w + off);    off = al(off + NBUCKETS * 4);
  float*  stats   = (float*)(w + off);  off = al(off + 512 * 4);       // sums[256] + ss[256]
  int*    rp      = (int*)(w + off);    off = al(off + (size_t)(N + 1) * 4);
  float*  deg_inv = (float*)(w + off);  off = al(off + (size_t)N * 4);
  int*    csr     = (int*)(w + off);    off = al(off + (size_t)E * 4);
  uint*   ebuf    = (uint*)(w + off);   off = al(off + (size_t)E * 4);
  ushort* Xb      = (ushort*)(w + off); off = al(off + (size_t)N * 128 * 2);
  ushort* hA      = (ushort*)(w + off); off = al(off + (size_t)N * 128 * 2);
  ushort* hB      = (ushort*)(w + off); off = al(off + (size_t)N * 128 * 2);
  ushort* W0l     = (ushort*)(w + off); off = al(off + 16384 * 2);
  ushort* W0r     = (ushort*)(w + off); off = al(off + 16384 * 2);
  ushort* W1l     = (ushort*)(w + off); off = al(off + 16384 * 2);
  ushort* W1r     = (ushort*)(w + off); off = al(off + 16384 * 2);
  ushort* Wc      = (ushort*)(w + off); off = al(off + 16384 * 2);
  const int nblkG = (N + 63) / 64;
  float*  partial = (float*)(w + off);  off = al(off + (size_t)nblkG * 256 * 4);

  const int nbBuck = (N + 1023) / 1024;
  const int binGrid = (E + 8191) / 8192;
  const int agg128Grid = (N + 15) / 16;
  const int agg47Grid = (N + 31) / 32;

  // casts + weight prep
  k_cast<<<2048, 256, 0, stream>>>(x, Xb, N * 32);
  k_prep_weights<<<128, 256, 0, stream>>>(Wl0, Wr0, Wl1, Wr1, Wl2, Wr2, W0l, W0r, W1l, W1r, Wc, C);

  // bucketed CSR build
  hipMemsetAsync(bcnt, 0, NBUCKETS * 4, stream);
  k_bucket_hist<<<256, 256, 0, stream>>>(edst, E, bcnt);
  k_bucket_scan<<<1, 128, 0, stream>>>(bcnt, brp, bcur);
  k_binscatter<<<binGrid, 256, 0, stream>>>(edst, esrc, E, bcur, ebuf);
  k_bucket_build<<<nbBuck, 512, 0, stream>>>(ebuf, brp, rp, deg_inv, csr, N, E);

  // Layer 0
  k_agg128<<<agg128Grid, 256, 0, stream>>>(Xb, rp, csr, deg_inv, hA, N);
  k_gemm_dual<<<nblkG, 256, 0, stream>>>(hA, Xb, W0l, W0r, partial, hB, N);
  hipMemsetAsync(stats, 0, 256 * 4, stream);
  k_bn_reduce<<<64, 256, 0, stream>>>(partial, nblkG, stats);
  k_bn_finalize<<<1, 128, 0, stream>>>(stats, g0, b0, N, stats + 256);
  k_bn_relu<<<2048, 256, 0, stream>>>((uint2*)hB, N * 32, stats + 256);

  // Layer 1 (in-place into hB: each block reads only its own rows, staged before stores)
  k_agg128<<<agg128Grid, 256, 0, stream>>>(hB, rp, csr, deg_inv, hA, N);
  k_gemm_dual<<<nblkG, 256, 0, stream>>>(hA, hB, W1l, W1r, partial, hB, N);
  hipMemsetAsync(stats, 0, 256 * 4, stream);
  k_bn_reduce<<<64, 256, 0, stream>>>(partial, nblkG, stats);
  k_bn_finalize<<<1, 128, 0, stream>>>(stats, g1, b1, N, stats + 256);
  k_bn_relu<<<2048, 256, 0, stream>>>((uint2*)hB, N * 32, stats + 256);

  // Layer 2: transform first (mean is linear), then aggregate in C-dim space
  k_gemm_single<<<nblkG, 256, 0, stream>>>(hB, Wc, hA, N);
  k_agg47<<<agg47Grid, 256, 0, stream>>>(hA, bl2, rp, csr, deg_inv, (float*)d_out, N, C);
}

// Round 6
// 348.798 us; speedup vs baseline: 5.5783x; 1.2430x over previous
//
#include <hip/hip_runtime.h>

typedef __attribute__((ext_vector_type(8))) short short8;
typedef __attribute__((ext_vector_type(4))) float f32x4;

constexpr float BN_EPS = 1e-5f;
#define NBUCKETS 128  // buckets of 1024 nodes; N <= 131072

__device__ __forceinline__ ushort f2bf(float f) {
  uint u = __float_as_uint(f);
  u = (u + 0x7fffu + ((u >> 16) & 1u)) >> 16;
  return (ushort)u;
}
__device__ __forceinline__ float bf2f(ushort h) { return __uint_as_float((uint)h << 16); }
__device__ __forceinline__ float bf2f_lo(uint v) { return __uint_as_float(v << 16); }
__device__ __forceinline__ float bf2f_hi(uint v) { return __uint_as_float(v & 0xffff0000u); }

typedef __attribute__((address_space(1))) const unsigned int* as1_cu32;
typedef __attribute__((address_space(3))) unsigned int* as3_u32;
__device__ __forceinline__ void gload_lds16(const void* g, void* l) {
  __builtin_amdgcn_global_load_lds((as1_cu32)g, (as3_u32)l, 16, 0, 0);
}

// ---------------- fp32 -> bf16 cast (x) ----------------

__global__ __launch_bounds__(256) void k_cast(const float* __restrict__ in, ushort* __restrict__ out, int n4) {
  for (int i = blockIdx.x * 256 + threadIdx.x; i < n4; i += gridDim.x * 256) {
    float4 v = reinterpret_cast<const float4*>(in)[i];
    ushort4 o;
    o.x = f2bf(v.x); o.y = f2bf(v.y); o.z = f2bf(v.z); o.w = f2bf(v.w);
    reinterpret_cast<ushort4*>(out)[i] = o;
  }
}

// all weight preps in one launch: blocks 0-63 cast the 4 128x128 weights,
// blocks 64-127 build the packed layer-2 weight (rows 0..C-1=Wl2, 64..64+C-1=Wr2, rest 0)
__global__ __launch_bounds__(256) void k_prep_weights(const float* __restrict__ Wl0, const float* __restrict__ Wr0,
                                                      const float* __restrict__ Wl1, const float* __restrict__ Wr1,
                                                      const float* __restrict__ Wl2, const float* __restrict__ Wr2,
                                                      ushort* __restrict__ W0l, ushort* __restrict__ W0r,
                                                      ushort* __restrict__ W1l, ushort* __restrict__ W1r,
                                                      ushort* __restrict__ Wc, int C) {
  int b = blockIdx.x;
  if (b < 64) {
    const float* src = (b < 16) ? Wl0 : (b < 32) ? Wr0 : (b < 48) ? Wl1 : Wr1;
    ushort* dst = (b < 16) ? W0l : (b < 32) ? W0r : (b < 48) ? W1l : W1r;
    int i = (b & 15) * 256 + threadIdx.x;  // 4096 float4 per matrix
    float4 v = reinterpret_cast<const float4*>(src)[i];
    ushort4 o;
    o.x = f2bf(v.x); o.y = f2bf(v.y); o.z = f2bf(v.z); o.w = f2bf(v.w);
    reinterpret_cast<ushort4*>(dst)[i] = o;
  } else {
    int i = (b - 64) * 256 + threadIdx.x;  // 16384
    int r = i >> 7, k = i & 127;
    float v = 0.f;
    if (r < C) v = Wl2[r * 128 + k];
    else if (r >= 64 && r < 64 + C) v = Wr2[(r - 64) * 128 + k];
    Wc[i] = f2bf(v);
  }
}

// ---------------- bucketed CSR build ----------------

__global__ __launch_bounds__(256) void k_bucket_hist(const int* __restrict__ dst, int E, int* __restrict__ bcnt) {
  __shared__ int h[NBUCKETS];
  for (int i = threadIdx.x; i < NBUCKETS; i += 256) h[i] = 0;
  __syncthreads();
  for (int i = blockIdx.x * 256 + threadIdx.x; i < E; i += gridDim.x * 256)
    atomicAdd(&h[dst[i] >> 10], 1);
  __syncthreads();
  for (int i = threadIdx.x; i < NBUCKETS; i += 256)
    if (h[i]) atomicAdd(&bcnt[i], h[i]);
}

__global__ __launch_bounds__(128) void k_bucket_scan(const int* __restrict__ bcnt, int* __restrict__ brp,
                                                     int* __restrict__ bcur) {
  __shared__ int sh[NBUCKETS];
  int tid = threadIdx.x;
  int v = bcnt[tid];
  sh[tid] = v;
  __syncthreads();
  for (int off = 1; off < NBUCKETS; off <<= 1) {
    int t = (tid >= off) ? sh[tid - off] : 0;
    __syncthreads();
    sh[tid] += t;
    __syncthreads();
  }
  int ex = sh[tid] - v;
  brp[tid] = ex;
  bcur[tid] = ex;
  if (tid == NBUCKETS - 1) brp[NBUCKETS] = sh[tid];
}

// bin edges into bucket-segmented packed array: (dst & 1023) | (src << 10)
__global__ __launch_bounds__(256) void k_binscatter(const int* __restrict__ dst, const int* __restrict__ src, int E,
                                                    int* __restrict__ bcur, uint* __restrict__ ebuf) {
  __shared__ int h[NBUCKETS];
  __shared__ int base[NBUCKETS];
  __shared__ int cur[NBUCKETS];
  const int e0 = blockIdx.x * 8192;
  const int e1 = min(e0 + 8192, E);
  for (int i = threadIdx.x; i < NBUCKETS; i += 256) h[i] = 0;
  __syncthreads();
  for (int e = e0 + threadIdx.x; e < e1; e += 256) atomicAdd(&h[dst[e] >> 10], 1);
  __syncthreads();
  if (threadIdx.x < NBUCKETS) {
    base[threadIdx.x] = atomicAdd(&bcur[threadIdx.x], h[threadIdx.x]);
    cur[threadIdx.x] = 0;
  }
  __syncthreads();
  for (int e = e0 + threadIdx.x; e < e1; e += 256) {
    int d = dst[e];
    int b = d >> 10;
    int pos = base[b] + atomicAdd(&cur[b], 1);
    ebuf[pos] = (uint)(d & 1023) | ((uint)src[e] << 10);
  }
}

// per-bucket: node counts, LDS scan, rp/deg_inv, scatter src into csr (all atomics in LDS)
__global__ __launch_bounds__(512) void k_bucket_build(const uint* __restrict__ ebuf, const int* __restrict__ brp,
                                                      int* __restrict__ rp, float* __restrict__ deg_inv,
                                                      int* __restrict__ csr, int N, int E) {
  __shared__ int cnt[1024];
  __shared__ int pre[1024];
  __shared__ int tmp[1024];
  const int blk = blockIdx.x, tid = threadIdx.x;
  const int base = blk << 10;
  const int p0 = brp[blk], p1 = brp[blk + 1];
  for (int i = tid; i < 1024; i += 512) cnt[i] = 0;
  __syncthreads();
  for (int p = p0 + tid; p < p1; p += 512) atomicAdd(&cnt[ebuf[p] & 1023u], 1);
  __syncthreads();
  for (int i = tid; i < 1024; i += 512) pre[i] = cnt[i];
  __syncthreads();
  for (int off = 1; off < 1024; off <<= 1) {
    for (int i = tid; i < 1024; i += 512) tmp[i] = (i >= off) ? pre[i - off] : 0;
    __syncthreads();
    for (int i = tid; i < 1024; i += 512) pre[i] += tmp[i];
    __syncthreads();
  }
  for (int i = tid; i < 1024; i += 512) {
    int node = base + i;
    if (node < N) {
      int ex = pre[i] - cnt[i];
      rp[node] = p0 + ex;
      deg_inv[node] = 1.0f / (float)max(cnt[i], 1);
    }
    tmp[i] = pre[i] - cnt[i];  // scatter cursor
  }
  if (tid == 0 && blk == gridDim.x - 1) rp[N] = E;
  __syncthreads();
  for (int p = p0 + tid; p < p1; p += 512) {
    uint pr = ebuf[p];
    int pos = p0 + atomicAdd(&tmp[pr & 1023u], 1);
    csr[pos] = (int)(pr >> 10);
  }
}

// ---------------- aggregation (bf16 rows; 4 nodes/wave, 16 lanes x 16B per row) ----------------

__global__ __launch_bounds__(256) void k_agg128(const ushort* __restrict__ X, const int* __restrict__ rp,
                                                const int* __restrict__ csr, const float* __restrict__ deg_inv,
                                                ushort* __restrict__ out, int N) {
  const int wave = threadIdx.x >> 6, lane = threadIdx.x & 63;
  const int sub = lane >> 4, li = lane & 15;
  const int node = blockIdx.x * 16 + wave * 4 + sub;
  if (node >= N) return;
  const int start = rp[node];
  const int c = rp[node + 1] - start;
  const uint4* X16 = reinterpret_cast<const uint4*>(X);
  float a0 = 0.f, a1 = 0.f, a2 = 0.f, a3 = 0.f, a4 = 0.f, a5 = 0.f, a6 = 0.f, a7 = 0.f;
  int p = 0;
  for (; p + 7 < c; p += 8) {
    int idx[8];
#pragma unroll
    for (int u = 0; u < 8; ++u) idx[u] = csr[start + p + u];
    uint4 v[8];
#pragma unroll
    for (int u = 0; u < 8; ++u) v[u] = X16[(size_t)idx[u] * 16 + li];
#pragma unroll
    for (int u = 0; u < 8; ++u) {
      a0 += bf2f_lo(v[u].x); a1 += bf2f_hi(v[u].x);
      a2 += bf2f_lo(v[u].y); a3 += bf2f_hi(v[u].y);
      a4 += bf2f_lo(v[u].z); a5 += bf2f_hi(v[u].z);
      a6 += bf2f_lo(v[u].w); a7 += bf2f_hi(v[u].w);
    }
  }
  if (p + 3 < c) {
    int idx[4];
#pragma unroll
    for (int u = 0; u < 4; ++u) idx[u] = csr[start + p + u];
    uint4 v[4];
#pragma unroll
    for (int u = 0; u < 4; ++u) v[u] = X16[(size_t)idx[u] * 16 + li];
#pragma unroll
    for (int u = 0; u < 4; ++u) {
      a0 += bf2f_lo(v[u].x); a1 += bf2f_hi(v[u].x);
      a2 += bf2f_lo(v[u].y); a3 += bf2f_hi(v[u].y);
      a4 += bf2f_lo(v[u].z); a5 += bf2f_hi(v[u].z);
      a6 += bf2f_lo(v[u].w); a7 += bf2f_hi(v[u].w);
    }
    p += 4;
  }
  for (; p < c; ++p) {
    uint4 v = X16[(size_t)csr[start + p] * 16 + li];
    a0 += bf2f_lo(v.x); a1 += bf2f_hi(v.x);
    a2 += bf2f_lo(v.y); a3 += bf2f_hi(v.y);
    a4 += bf2f_lo(v.z); a5 += bf2f_hi(v.z);
    a6 += bf2f_lo(v.w); a7 += bf2f_hi(v.w);
  }
  const float di = deg_inv[node];
  uint4 o;
  o.x = (uint)f2bf(a0 * di) | ((uint)f2bf(a1 * di) << 16);
  o.y = (uint)f2bf(a2 * di) | ((uint)f2bf(a3 * di) << 16);
  o.z = (uint)f2bf(a4 * di) | ((uint)f2bf(a5 * di) << 16);
  o.w = (uint)f2bf(a6 * di) | ((uint)f2bf(a7 * di) << 16);
  reinterpret_cast<uint4*>(out)[(size_t)node * 16 + li] = o;
}

// ---------------- MFMA GEMM v3: wave-owned column tiles ----------------
// 512 threads = 8 waves; wave w owns output cols [16w,16w+16). Weights for the
// strip live in registers (8 short8). A/B tiles (64 rows x 128) staged via
// global_load_lds with PRE-SWIZZLED per-lane source (LDS dest linear; involution
// swizzle byte^=(row&7)<<4 applied on source and on ds_read). Z repacked through
// swizzled LDS for contiguous dwordx4 stores. DUAL adds B@WB^T and BN partials.

template <bool DUAL>
__global__ __launch_bounds__(512, 6) void k_gemm(const ushort* __restrict__ A, const ushort* __restrict__ B,
                                                 const ushort* __restrict__ WA, const ushort* __restrict__ WB,
                                                 float* __restrict__ partial, ushort* __restrict__ Z, int M) {
  __shared__ ushort sA[64 * 128];
  __shared__ ushort sB[DUAL ? 64 * 128 : 64];
  __shared__ ushort sZ[64 * 128];
  const int tid = threadIdx.x;
  const int wave = tid >> 6, lane = tid & 63;
  const int rfrag = lane & 15, kgrp = lane >> 4;
  const int row0 = blockIdx.x * 64;

  // stage: wave w fills chunks {2w, 2w+1}; chunk = 1KB = 4 rows; source pre-swizzled
#pragma unroll
  for (int i = 0; i < 2; ++i) {
    int c = wave * 2 + i;
    int lb = c * 1024 + lane * 16;
    int row = lb >> 8, bin = lb & 255;
    int gr = min(row0 + row, M - 1);
    int sb = bin ^ ((row & 7) << 4);
    gload_lds16((const char*)A + (size_t)gr * 256 + sb, (char*)sA + c * 1024);
    if (DUAL) gload_lds16((const char*)B + (size_t)gr * 256 + sb, (char*)sB + c * 1024);
  }

  // weight fragments for this wave's column strip -> registers
  short8 wfA[4], wfB[4];
  {
    const ushort* wa = WA + (wave * 16 + rfrag) * 128 + kgrp * 8;
#pragma unroll
    for (int s = 0; s < 4; ++s) wfA[s] = *reinterpret_cast<const short8*>(wa + s * 32);
    if (DUAL) {
      const ushort* wb = WB + (wave * 16 + rfrag) * 128 + kgrp * 8;
#pragma unroll
      for (int s = 0; s < 4; ++s) wfB[s] = *reinterpret_cast<const short8*>(wb + s * 32);
    }
  }
  __syncthreads();

  f32x4 acc[4];
#pragma unroll
  for (int i = 0; i < 4; ++i) acc[i] = (f32x4){0.f, 0.f, 0.f, 0.f};

  const int rs = (rfrag & 7) << 4;
#pragma unroll
  for (int strip = 0; strip < 4; ++strip) {
    const int r = strip * 16 + rfrag;
    short8 af[4];
#pragma unroll
    for (int s = 0; s < 4; ++s)
      af[s] = *reinterpret_cast<const short8*>((const char*)sA + r * 256 + ((kgrp * 16 + s * 64) ^ rs));
#pragma unroll
    for (int s = 0; s < 4; ++s)
      acc[strip] = __builtin_amdgcn_mfma_f32_16x16x32_bf16(af[s], wfA[s], acc[strip], 0, 0, 0);
    if (DUAL) {
      short8 bf[4];
#pragma unroll
      for (int s = 0; s < 4; ++s)
        bf[s] = *reinterpret_cast<const short8*>((const char*)sB + r * 256 + ((kgrp * 16 + s * 64) ^ rs));
#pragma unroll
      for (int s = 0; s < 4; ++s)
        acc[strip] = __builtin_amdgcn_mfma_f32_16x16x32_bf16(bf[s], wfB[s], acc[strip], 0, 0, 0);
    }
  }

  // BN partials (pre-rounding fp32), per-wave-owned columns -> direct global
  if (DUAL) {
    float s1 = 0.f, s2 = 0.f;
#pragma unroll
    for (int strip = 0; strip < 4; ++strip) {
#pragma unroll
      for (int rr = 0; rr < 4; ++rr) {
        int grow = row0 + strip * 16 + kgrp * 4 + rr;
        if (grow < M) {
          float v = acc[strip][rr];
          s1 += v;
          s2 = fmaf(v, v, s2);
        }
      }
    }
    s1 += __shfl_xor(s1, 16); s2 += __shfl_xor(s2, 16);
    s1 += __shfl_xor(s1, 32); s2 += __shfl_xor(s2, 32);
    if (kgrp == 0) {
      partial[(size_t)blockIdx.x * 256 + wave * 16 + rfrag] = s1;
      partial[(size_t)blockIdx.x * 256 + 128 + wave * 16 + rfrag] = s2;
    }
  }

  // repack into swizzled sZ
  const int cb = (wave * 16 + rfrag) * 2;
#pragma unroll
  for (int strip = 0; strip < 4; ++strip) {
#pragma unroll
    for (int rr = 0; rr < 4; ++rr) {
      int row = strip * 16 + kgrp * 4 + rr;
      *reinterpret_cast<ushort*>((char*)sZ + row * 256 + (cb ^ ((row & 7) << 4))) = f2bf(acc[strip][rr]);
    }
  }
  __syncthreads();

  // contiguous Z store (unswizzle on read)
#pragma unroll
  for (int i = 0; i < 2; ++i) {
    int lb = (wave * 2 + i) * 1024 + lane * 16;
    int row = lb >> 8, bin = lb & 255;
    int gr = row0 + row;
    if (gr < M)
      *reinterpret_cast<uint4*>((char*)Z + (size_t)gr * 256 + bin) =
          *reinterpret_cast<const uint4*>((const char*)sZ + row * 256 + (bin ^ ((row & 7) << 4)));
  }
}

// ---------------- BN reduce / finalize / apply ----------------

__global__ __launch_bounds__(256) void k_bn_reduce(const float* __restrict__ partial, int nblk,
                                                   float* __restrict__ stats) {
  float acc = 0.f;
  for (int b = blockIdx.x; b < nblk; b += gridDim.x) acc += partial[(size_t)b * 256 + threadIdx.x];
  atomicAdd(&stats[threadIdx.x], acc);
}

__global__ __launch_bounds__(128) void k_bn_finalize(const float* __restrict__ sums, const float* __restrict__ g,
                                                     const float* __restrict__ b, int M, float* __restrict__ ss) {
  int f = threadIdx.x;
  float inv = 1.0f / (float)M;
  float mean = sums[f] * inv;
  float var = sums[128 + f] * inv - mean * mean;
  var = fmaxf(var, 0.f);
  float sc = g[f] * rsqrtf(var + BN_EPS);
  ss[f] = sc;
  ss[128 + f] = fmaf(-mean, sc, b[f]);
}

__global__ __launch_bounds__(256) void k_bn_relu(uint2* __restrict__ Z, int n2, const float* __restrict__ ss) {
  for (int i = blockIdx.x * 256 + threadIdx.x; i < n2; i += gridDim.x * 256) {
    uint2 v = Z[i];
    int f0 = (i & 31) * 4;
    float4 sc = *reinterpret_cast<const float4*>(&ss[f0]);
    float4 sh = *reinterpret_cast<const float4*>(&ss[128 + f0]);
    float a0 = fmaxf(fmaf(bf2f_lo(v.x), sc.x, sh.x), 0.f);
    float a1 = fmaxf(fmaf(bf2f_hi(v.x), sc.y, sh.y), 0.f);
    float a2 = fmaxf(fmaf(bf2f_lo(v.y), sc.z, sh.z), 0.f);
    float a3 = fmaxf(fmaf(bf2f_hi(v.y), sc.w, sh.w), 0.f);
    v.x = (uint)f2bf(a0) | ((uint)f2bf(a1) << 16);
    v.y = (uint)f2bf(a2) | ((uint)f2bf(a3) << 16);
    Z[i] = v;
  }
}

// ---------------- layer-2 aggregation: out = mean(Y) + R + bias (fp32 out) ----------------
// Z rows: cols 0..C-1 = Y, cols 64..64+C-1 = R; 8 nodes/wave, 8 lanes x 16B per row.

__global__ __launch_bounds__(256) void k_agg47(const ushort* __restrict__ Z, const float* __restrict__ bias,
                                               const int* __restrict__ rp, const int* __restrict__ csr,
                                               const float* __restrict__ deg_inv, float* __restrict__ out,
                                               int N, int C) {
  const int wave = threadIdx.x >> 6, lane = threadIdx.x & 63;
  const int sub = lane >> 3, li = lane & 7;
  const int node = blockIdx.x * 32 + wave * 8 + sub;
  if (node >= N) return;
  const int start = rp[node];
  const int c = rp[node + 1] - start;
  const uint4* Z16 = reinterpret_cast<const uint4*>(Z);
  float a0 = 0.f, a1 = 0.f, a2 = 0.f, a3 = 0.f, a4 = 0.f, a5 = 0.f, a6 = 0.f, a7 = 0.f;
  int p = 0;
  for (; p + 7 < c; p += 8) {
    int idx[8];
#pragma unroll
    for (int u = 0; u < 8; ++u) idx[u] = csr[start + p + u];
    uint4 v[8];
#pragma unroll
    for (int u = 0; u < 8; ++u) v[u] = Z16[(size_t)idx[u] * 16 + li];
#pragma unroll
    for (int u = 0; u < 8; ++u) {
      a0 += bf2f_lo(v[u].x); a1 += bf2f_hi(v[u].x);
      a2 += bf2f_lo(v[u].y); a3 += bf2f_hi(v[u].y);
      a4 += bf2f_lo(v[u].z); a5 += bf2f_hi(v[u].z);
      a6 += bf2f_lo(v[u].w); a7 += bf2f_hi(v[u].w);
    }
  }
  for (; p < c; ++p) {
    uint4 v = Z16[(size_t)csr[start + p] * 16 + li];
    a0 += bf2f_lo(v.x); a1 += bf2f_hi(v.x);
    a2 += bf2f_lo(v.y); a3 += bf2f_hi(v.y);
    a4 += bf2f_lo(v.z); a5 += bf2f_hi(v.z);
    a6 += bf2f_lo(v.w); a7 += bf2f_hi(v.w);
  }
  const float di = deg_inv[node];
  uint4 sv = Z16[(size_t)node * 16 + 8 + li];  // cols 64+li*8 .. +7
  float s[8] = {bf2f_lo(sv.x), bf2f_hi(sv.x), bf2f_lo(sv.y), bf2f_hi(sv.y),
                bf2f_lo(sv.z), bf2f_hi(sv.z), bf2f_lo(sv.w), bf2f_hi(sv.w)};
  float a[8] = {a0, a1, a2, a3, a4, a5, a6, a7};
#pragma unroll
  for (int j = 0; j < 8; ++j) {
    int f = li * 8 + j;
    if (f < C) out[(size_t)node * C + f] = fmaf(a[j], di, s[j] + bias[f]);
  }
}

// ---------------- host launch ----------------

extern "C" void kernel_launch(void* const* d_in, const int* in_sizes, int n_in,
                              void* d_out, int out_size, void* d_ws, size_t ws_size,
                              hipStream_t stream) {
  const float* x   = (const float*)d_in[0];
  const int*   ei  = (const int*)d_in[1];
  const float* Wl0 = (const float*)d_in[2];
  const float* Wr0 = (const float*)d_in[4];
  const float* g0  = (const float*)d_in[5];
  const float* b0  = (const float*)d_in[6];
  const float* Wl1 = (const float*)d_in[7];
  const float* Wr1 = (const float*)d_in[9];
  const float* g1  = (const float*)d_in[10];
  const float* b1  = (const float*)d_in[11];
  const float* Wl2 = (const float*)d_in[12];
  const float* bl2 = (const float*)d_in[13];
  const float* Wr2 = (const float*)d_in[14];

  const int N = in_sizes[0] / 128;
  const int E = in_sizes[1] / 2;
  const int C = in_sizes[13];  // 47

  const int* edst = ei;
  const int* esrc = ei + E;

  char* w = (char*)d_ws;
  auto al = [](size_t v) { return (v + 255) & ~(size_t)255; };
  size_t off = 0;
  int*    bcnt    = (int*)(w + off);    off = al(off + NBUCKETS * 4);
  int*    brp     = (int*)(w + off);    off = al(off + (NBUCKETS + 1) * 4);
  int*    bcur    = (int*)(w + off);    off = al(off + NBUCKETS * 4);
  float*  stats   = (float*)(w + off);  off = al(off + 512 * 4);       // sums[256] + ss[256]
  int*    rp      = (int*)(w + off);    off = al(off + (size_t)(N + 1) * 4);
  float*  deg_inv = (float*)(w + off);  off = al(off + (size_t)N * 4);
  int*    csr     = (int*)(w + off);    off = al(off + (size_t)E * 4);
  uint*   ebuf    = (uint*)(w + off);   off = al(off + (size_t)E * 4);
  ushort* Xb      = (ushort*)(w + off); off = al(off + (size_t)N * 128 * 2);
  ushort* hA      = (ushort*)(w + off); off = al(off + (size_t)N * 128 * 2);
  ushort* hB      = (ushort*)(w + off); off = al(off + (size_t)N * 128 * 2);
  ushort* W0l     = (ushort*)(w + off); off = al(off + 16384 * 2);
  ushort* W0r     = (ushort*)(w + off); off = al(off + 16384 * 2);
  ushort* W1l     = (ushort*)(w + off); off = al(off + 16384 * 2);
  ushort* W1r     = (ushort*)(w + off); off = al(off + 16384 * 2);
  ushort* Wc      = (ushort*)(w + off); off = al(off + 16384 * 2);
  const int nblkG = (N + 63) / 64;
  float*  partial = (float*)(w + off);  off = al(off + (size_t)nblkG * 256 * 4);

  const int nbBuck = (N + 1023) / 1024;
  const int binGrid = (E + 8191) / 8192;
  const int agg128Grid = (N + 15) / 16;
  const int agg47Grid = (N + 31) / 32;

  // casts + weight prep
  k_cast<<<2048, 256, 0, stream>>>(x, Xb, N * 32);
  k_prep_weights<<<128, 256, 0, stream>>>(Wl0, Wr0, Wl1, Wr1, Wl2, Wr2, W0l, W0r, W1l, W1r, Wc, C);

  // bucketed CSR build
  hipMemsetAsync(bcnt, 0, NBUCKETS * 4, stream);
  k_bucket_hist<<<256, 256, 0, stream>>>(edst, E, bcnt);
  k_bucket_scan<<<1, 128, 0, stream>>>(bcnt, brp, bcur);
  k_binscatter<<<binGrid, 256, 0, stream>>>(edst, esrc, E, bcur, ebuf);
  k_bucket_build<<<nbBuck, 512, 0, stream>>>(ebuf, brp, rp, deg_inv, csr, N, E);

  // Layer 0
  k_agg128<<<agg128Grid, 256, 0, stream>>>(Xb, rp, csr, deg_inv, hA, N);
  k_gemm<true><<<nblkG, 512, 0, stream>>>(hA, Xb, W0l, W0r, partial, hB, N);
  hipMemsetAsync(stats, 0, 256 * 4, stream);
  k_bn_reduce<<<64, 256, 0, stream>>>(partial, nblkG, stats);
  k_bn_finalize<<<1, 128, 0, stream>>>(stats, g0, b0, N, stats + 256);
  k_bn_relu<<<2048, 256, 0, stream>>>((uint2*)hB, N * 32, stats + 256);

  // Layer 1 (in-place into hB: each block stages its own rows before storing them)
  k_agg128<<<agg128Grid, 256, 0, stream>>>(hB, rp, csr, deg_inv, hA, N);
  k_gemm<true><<<nblkG, 512, 0, stream>>>(hA, hB, W1l, W1r, partial, hB, N);
  hipMemsetAsync(stats, 0, 256 * 4, stream);
  k_bn_reduce<<<64, 256, 0, stream>>>(partial, nblkG, stats);
  k_bn_finalize<<<1, 128, 0, stream>>>(stats, g1, b1, N, stats + 256);
  k_bn_relu<<<2048, 256, 0, stream>>>((uint2*)hB, N * 32, stats + 256);

  // Layer 2: transform first (mean is linear), then aggregate in C-dim space
  k_gemm<false><<<nblkG, 512, 0, stream>>>(hB, nullptr, Wc, nullptr, nullptr, hA, N);
  k_agg47<<<agg47Grid, 256, 0, stream>>>(hA, bl2, rp, csr, deg_inv, (float*)d_out, N, C);
}